// Round 12
// baseline (451.643 us; speedup 1.0000x reference)
//
#include <hip/hip_runtime.h>

// GCN3: 3x (COO spmm -> Linear(64) -> ReLU), segment-mean pool, softmax head.
// relu(spmm(X)@W + b) == relu(spmm(X@W) + b): dense transform first, then
// PULL-spmm from fp8 Z (e4m3). Edge record 4B: (col<<14)|fp8(val*16).
// spmm v12: Z stored as TWO PHYSICAL HALVES ZqLo/ZqHi (dims 0-31/32-63,
// 32B/row = 3.2MB each); each layer = two dispatches, one per half. v11
// counters: FETCH 125MB/dispatch = gather stream missing L2 (6.4MB Zq >
// 4MB per-XCD L2, random cols -> every XCD needs all rows -> 32x reuse
// never captured). 3.2MB half fits L2 -> reuse captured. Split must be
// physical: strided half-rows would still touch every 64B line.
// cvt/fma + reduce tree conserved (bit-identical per-dim FP order);
// duplicated: epk c-loads + rp + addressing (~+27% VALU at 58% busy).
// Per-dispatch: deg-adaptive single predicated burst (v11), dwordx2
// gathers (16 slots x 32B rows = 16 lines in flight), byte off = rec>>9.
// CSR build: LDS-staged binpass + per-bucket counting sort. DO NOT replace
// with direct global scatter (v9 ERRATA): 4B scatter lines fed from
// multiple XCDs = 16x write amplification (measured 195MB for 12.8MB);
// binpass guarantees every epk line is produced by ONE CU.
// dense64: MFMA 16x16x32 bf16, W staged in LDS per block.

#define BSHIFT 9
#define BROWS  (1 << BSHIFT)   // 512 rows per bucket
#define MAXK   256             // supports N <= 131072
#define CHUNK  6144            // edges per binpass/bhist block

typedef float f32x2 __attribute__((ext_vector_type(2)));
typedef float f32x4 __attribute__((ext_vector_type(4)));
typedef unsigned u32x2 __attribute__((ext_vector_type(2)));
typedef unsigned u32x4 __attribute__((ext_vector_type(4)));
typedef short bf16x8 __attribute__((ext_vector_type(8)));

__device__ inline unsigned char f2q(float f) {  // fp8 e4m3 RNE (saturating)
    unsigned p = __builtin_amdgcn_cvt_pk_fp8_f32(f, f, 0u, false);
    return (unsigned char)(p & 0xffu);
}
template <int SEL>
__device__ inline float q2f(unsigned q) {  // byte-select fp8->f32 (SEL = ICE)
    return __builtin_amdgcn_cvt_f32_fp8(q, SEL);
}
template <int HI>  // 2 fp8 (bytes 2*HI, 2*HI+1) -> 2 f32, one instr
__device__ inline f32x2 q2f2(unsigned q) {
#if __has_builtin(__builtin_amdgcn_cvt_pk_f32_fp8)
    return __builtin_amdgcn_cvt_pk_f32_fp8(q, HI != 0);
#else
    f32x2 r;
    r.x = q2f<2 * HI>(q);
    r.y = q2f<2 * HI + 1>(q);
    return r;
#endif
}

// pack 8 f32 (k ascending: lo.x..lo.w, hi.x..hi.w) -> bf16x8, RNE
__device__ inline bf16x8 pack_bf8(f32x4 lo, f32x4 hi) {
    union { u32x4 u; bf16x8 h; } r;
    asm("v_cvt_pk_bf16_f32 %0, %1, %2" : "=v"(r.u.x) : "v"(lo.x), "v"(lo.y));
    asm("v_cvt_pk_bf16_f32 %0, %1, %2" : "=v"(r.u.y) : "v"(lo.z), "v"(lo.w));
    asm("v_cvt_pk_bf16_f32 %0, %1, %2" : "=v"(r.u.z) : "v"(hi.x), "v"(hi.y));
    asm("v_cvt_pk_bf16_f32 %0, %1, %2" : "=v"(r.u.w) : "v"(hi.z), "v"(hi.w));
    return r.h;
}

// Per-block LDS histogram of bucket ids -> global bucket counts.
// Also zeroes the pool buffers (sums/cnts), grid-strided.
__global__ __launch_bounds__(512) void bhist_k(const int* __restrict__ rows,
                                               int* __restrict__ bhist,
                                               float* __restrict__ sums,
                                               int* __restrict__ cnts,
                                               int E, int G) {
    __shared__ int h[MAXK];
    int tx = threadIdx.x;
    if (tx < MAXK) h[tx] = 0;
    int gstep = gridDim.x * 512, gid = blockIdx.x * 512 + tx;
    f32x4* s4 = (f32x4*)sums;
    for (int i = gid; i < G * 16; i += gstep) s4[i] = 0;
    for (int i = gid; i < G; i += gstep) cnts[i] = 0;
    __syncthreads();
    int e0 = blockIdx.x * CHUNK, ee = min(e0 + CHUNK, E);
    for (int e = e0 + tx; e < ee; e += 512)
        atomicAdd(&h[rows[e] >> BSHIFT], 1);
    __syncthreads();
    if (tx < MAXK && h[tx]) atomicAdd(&bhist[tx], h[tx]);
}

// Exclusive scan of bucket counts (single block); init padded cursors; rp[N]=E.
__global__ __launch_bounds__(MAXK) void bscan_k(const int* __restrict__ bhist,
                                                int* __restrict__ bstart,
                                                int* __restrict__ bcur,
                                                int* __restrict__ rp,
                                                int K, int E, int N) {
    __shared__ int s[MAXK];
    int tx = threadIdx.x;
    int v = (tx < K) ? bhist[tx] : 0;
    s[tx] = v;
    __syncthreads();
    for (int off = 1; off < MAXK; off <<= 1) {
        int t = (tx >= off) ? s[tx - off] : 0;
        __syncthreads();
        s[tx] += t;
        __syncthreads();
    }
    if (tx < K) {
        bstart[tx] = s[tx] - v;
        bcur[tx * 16] = s[tx] - v;  // 1 cursor per 64B line
    }
    if (tx == K - 1) bstart[K] = E;
    if (tx == 0) rp[N] = E;
}

// Bin edges by 512-row bucket, staged in LDS so global writes are ~31-edge
// single-CU bursts. Record (u64): lo32=(col<<9)|(row&511), hi32=val bits.
__global__ __launch_bounds__(512) void binpass_k(
    const int* __restrict__ rows, const int* __restrict__ cols,
    const float* __restrict__ vals, int* __restrict__ bcur,
    unsigned long long* __restrict__ pk, int E) {
    __shared__ int h[MAXK], base[MAXK], gbase[MAXK], lcnt[MAXK];
    __shared__ unsigned long long st[CHUNK];  // 48 KB
    int tx = threadIdx.x;
    if (tx < MAXK) h[tx] = 0;
    __syncthreads();
    int e0 = blockIdx.x * CHUNK, ee = min(e0 + CHUNK, E);
    for (int e = e0 + tx; e < ee; e += 512)
        atomicAdd(&h[rows[e] >> BSHIFT], 1);
    __syncthreads();
    int v = (tx < MAXK) ? h[tx] : 0;
    if (tx < MAXK) lcnt[tx] = v;  // scan buffer
    __syncthreads();
    for (int off = 1; off < MAXK; off <<= 1) {
        int t = (tx >= off && tx < MAXK) ? lcnt[tx - off] : 0;
        __syncthreads();
        if (tx < MAXK) lcnt[tx] += t;
        __syncthreads();
    }
    if (tx < MAXK) {
        base[tx] = lcnt[tx] - v;
        if (v) gbase[tx] = atomicAdd(&bcur[tx * 16], v);
        lcnt[tx] = 0;
    }
    __syncthreads();
    for (int e = e0 + tx; e < ee; e += 512) {
        int r = rows[e];
        int c = cols[e];
        float vv = vals[e];
        int b = r >> BSHIFT;
        int p = base[b] + atomicAdd(&lcnt[b], 1);
        unsigned lo = ((unsigned)c << BSHIFT) | (unsigned)(r & (BROWS - 1));
        st[p] = (unsigned long long)lo
              | ((unsigned long long)(unsigned)__float_as_int(vv) << 32);
    }
    __syncthreads();
    // flush contiguous per-bucket runs, wave-parallel. NT safe: 64 lanes x 8B
    // = 512B contiguous per instruction (full lines covered).
    int lane = tx & 63, wid = tx >> 6;
    for (int b = wid; b < MAXK; b += 8) {
        int cnt = h[b];
        if (!cnt) continue;
        int lb = base[b], gb = gbase[b];
        for (int i = lane; i < cnt; i += 64)
            __builtin_nontemporal_store(st[lb + i], &pk[gb + i]);
    }
}

// Per-bucket counting sort: one block per bucket. LDS hist over 512 rows,
// scan -> rp, then local scatter into the bucket's contiguous epk window.
// CACHED loads/stores (sub-line scatter within ONE block's window: single-CU
// production of each line, L2-local assembly).
// Output record (4B): (col << 14) | fp8(val * 16).
__global__ __launch_bounds__(512) void sort_k(
    const int* __restrict__ bstart, const unsigned long long* __restrict__ pk,
    int* __restrict__ rp, unsigned* __restrict__ epk, int n) {
    __shared__ int hist[BROWS], cur[BROWS];
    int tx = threadIdx.x;
    int b = blockIdx.x;
    int row0 = b << BSHIFT;
    int s = bstart[b], e = bstart[b + 1];
    hist[tx] = 0;
    __syncthreads();
    for (int j = s + tx; j < e; j += 512) {
        unsigned lo = (unsigned)pk[j];
        atomicAdd(&hist[lo & (BROWS - 1)], 1);
    }
    __syncthreads();
    int v = hist[tx];
    for (int off = 1; off < BROWS; off <<= 1) {
        int t = (tx >= off) ? hist[tx - off] : 0;
        __syncthreads();
        hist[tx] += t;
        __syncthreads();
    }
    int excl = hist[tx] - v;
    cur[tx] = excl;
    if (row0 + tx < n) rp[row0 + tx] = s + excl;
    __syncthreads();
    for (int j = s + tx; j < e; j += 512) {
        unsigned long long rec = pk[j];
        unsigned lo = (unsigned)rec;
        float vv = __int_as_float((int)(unsigned)(rec >> 32));
        int r = (int)(lo & (BROWS - 1));
        int q = atomicAdd(&cur[r], 1);
        epk[s + q] = ((lo >> BSHIFT) << 14) | (unsigned)f2q(vv * 16.f);
    }
}

// Z halves = fp8(X @ W1), X:[n,5]. Wave per row, lane = out dim.
__global__ __launch_bounds__(256) void dense5_k(
    const float* __restrict__ X, const float* __restrict__ W,
    unsigned char* __restrict__ ZLo, unsigned char* __restrict__ ZHi, int n) {
    int lane = threadIdx.x & 63;
    int row = (blockIdx.x * blockDim.x + threadIdx.x) >> 6;
    if (row >= n) return;
    float w0 = W[lane], w1 = W[64 + lane], w2 = W[128 + lane],
          w3 = W[192 + lane], w4 = W[256 + lane];
    float xv = (lane < 5) ? X[(size_t)row * 5 + lane] : 0.f;
    float y = __shfl(xv, 0, 64) * w0;
    y = fmaf(__shfl(xv, 1, 64), w1, y);
    y = fmaf(__shfl(xv, 2, 64), w2, y);
    y = fmaf(__shfl(xv, 3, 64), w3, y);
    y = fmaf(__shfl(xv, 4, 64), w4, y);
    unsigned char* dst = (lane < 32) ? (ZLo + (size_t)row * 32 + lane)
                                     : (ZHi + (size_t)row * 32 + lane - 32);
    *dst = f2q(y);
}

// dense64: Z halves = fp8(X @ W) via mfma_f32_16x16x32_bf16. W staged into
// LDS coalesced once per block; stride 65 -> conflict-free fragment reads.
// Wave = 16-row tile x 64 cols; frag (c,m) holds B[k=32m+8lk+i][col=16c+l15].
// Epilogue: cols 0-31 -> ZLo[r*32 + ...], cols 32-63 -> ZHi.
__global__ __launch_bounds__(256, 4) void dense64_k(
    const float* __restrict__ X, const float* __restrict__ W,
    unsigned char* __restrict__ ZLo, unsigned char* __restrict__ ZHi, int n) {
    __shared__ float wlds[64 * 65];
    int tx = threadIdx.x;
    int lane = tx & 63, wid = tx >> 6;
    int l15 = lane & 15, lk = lane >> 4;
#pragma unroll
    for (int i = 0; i < 16; ++i) {
        int idx = i * 256 + tx;              // coalesced: 1KB per instr
        wlds[(idx >> 6) * 65 + (idx & 63)] = W[idx];
    }
    __syncthreads();
    bf16x8 bw[4][2];
#pragma unroll
    for (int c = 0; c < 4; ++c) {
#pragma unroll
        for (int m = 0; m < 2; ++m) {
            const float* wp = wlds + (32 * m + 8 * lk) * 65 + 16 * c + l15;
            f32x4 lo, hi;
            lo.x = wp[0];       lo.y = wp[65];      lo.z = wp[130];  lo.w = wp[195];
            hi.x = wp[260];     hi.y = wp[325];     hi.z = wp[390];  hi.w = wp[455];
            bw[c][m] = pack_bf8(lo, hi);
        }
    }
    int nt = (n + 15) >> 4;
    int nwv = (int)(gridDim.x * 4);
    for (int t = blockIdx.x * 4 + wid; t < nt; t += nwv) {
        int rowb = t << 4;
        int ar = min(rowb + l15, n - 1);  // clamped A row (stores guarded)
        const float* xr = X + (size_t)ar * 64 + 8 * lk;
        f32x4 a0 = *(const f32x4*)(xr);
        f32x4 a1 = *(const f32x4*)(xr + 4);
        f32x4 a2 = *(const f32x4*)(xr + 32);
        f32x4 a3 = *(const f32x4*)(xr + 36);
        bf16x8 A0 = pack_bf8(a0, a1);
        bf16x8 A1 = pack_bf8(a2, a3);
        f32x4 acc0 = 0, acc1 = 0, acc2 = 0, acc3 = 0;
        acc0 = __builtin_amdgcn_mfma_f32_16x16x32_bf16(A0, bw[0][0], acc0, 0, 0, 0);
        acc1 = __builtin_amdgcn_mfma_f32_16x16x32_bf16(A0, bw[1][0], acc1, 0, 0, 0);
        acc2 = __builtin_amdgcn_mfma_f32_16x16x32_bf16(A0, bw[2][0], acc2, 0, 0, 0);
        acc3 = __builtin_amdgcn_mfma_f32_16x16x32_bf16(A0, bw[3][0], acc3, 0, 0, 0);
        acc0 = __builtin_amdgcn_mfma_f32_16x16x32_bf16(A1, bw[0][1], acc0, 0, 0, 0);
        acc1 = __builtin_amdgcn_mfma_f32_16x16x32_bf16(A1, bw[1][1], acc1, 0, 0, 0);
        acc2 = __builtin_amdgcn_mfma_f32_16x16x32_bf16(A1, bw[2][1], acc2, 0, 0, 0);
        acc3 = __builtin_amdgcn_mfma_f32_16x16x32_bf16(A1, bw[3][1], acc3, 0, 0, 0);
#pragma unroll
        for (int j = 0; j < 4; ++j) {
            int r = rowb + 4 * lk + j;
            if (r < n) {
                unsigned char* zlo = ZLo + (size_t)r * 32 + l15;
                unsigned char* zhi = ZHi + (size_t)r * 32 + l15;
                zlo[0]  = f2q(acc0[j]);   // cols 0-15
                zlo[16] = f2q(acc1[j]);   // cols 16-31
                zhi[0]  = f2q(acc2[j]);   // cols 32-47
                zhi[16] = f2q(acc3[j]);   // cols 48-63
            }
        }
    }
}

// Packed core: one edge's 8B Z-half chunk into a2[0..3] (f32x2 = 2 dims).
// 4 cvt_pk + 4 pk_fma per edge per dispatch (total over 2 dispatches = v11).
#define FMA8P(vv2, d)                                                          \
    a2[0] += (vv2) * q2f2<0>((d).x);                                           \
    a2[1] += (vv2) * q2f2<1>((d).x);                                           \
    a2[2] += (vv2) * q2f2<0>((d).y);                                           \
    a2[3] += (vv2) * q2f2<1>((d).y);

// spmm v12: wave per row; 16 edge-slots (lane>>2) x 4 dim-lanes (lane&3),
// 8 dims (8B) per lane from ONE 3.2MB Z-half (L2-resident per XCD).
// Deg-adaptive single predicated burst; dwordx2 gathers (16 lines/instr);
// byte offset = rec>>9 (col*32). hofs = 0 or 32 selects output dims.
template <int L3>
__global__ __launch_bounds__(256, 8) void spmm16_k(
    const int* __restrict__ rp, const unsigned* __restrict__ epk,
    const unsigned char* __restrict__ Zq, const float* __restrict__ bias,
    const float* __restrict__ xa, const float* __restrict__ xb,
    float* __restrict__ xout, int n, int hofs) {
    int lane = threadIdx.x & 63;
    int dim4 = lane & 3, slot = lane >> 2;
    int row = __builtin_amdgcn_readfirstlane(
        (int)((blockIdx.x * blockDim.x + threadIdx.x) >> 6));
    if (row >= n) return;
    int s = rp[row], e = rp[row + 1];    // scalar loads (wave-uniform row)
    const unsigned char* zb = Zq + (dim4 << 3);

    f32x2 a2[4];
#pragma unroll
    for (int k = 0; k < 4; ++k) a2[k] = 0;

    if (e - s <= 32) {  // ~55% of rows (Poisson(32)): 32-slot burst
        int i0 = min(s + slot, e - 1);
        int i1 = min(s + 16 + slot, e - 1);
        unsigned c0 = __builtin_nontemporal_load(epk + i0);
        unsigned c1 = __builtin_nontemporal_load(epk + i1);
        u32x2 d0 = *(const u32x2*)(zb + (c0 >> 9));  // c>>9 = col*32
        u32x2 d1 = *(const u32x2*)(zb + (c1 >> 9));
        float v0 = (s + slot < e) ? q2f<0>(c0) : 0.f;
        float v1 = (s + 16 + slot < e) ? q2f<0>(c1) : 0.f;
        f32x2 vv0 = {v0, v0}, vv1 = {v1, v1};
        FMA8P(vv0, d0)
        FMA8P(vv1, d1)
    } else {
        int j = s;
        for (; j + 64 <= e; j += 64) {  // rare (P ~ 6e-7): full 64-bursts
            unsigned c0 = __builtin_nontemporal_load(epk + j + slot);
            unsigned c1 = __builtin_nontemporal_load(epk + j + 16 + slot);
            unsigned c2 = __builtin_nontemporal_load(epk + j + 32 + slot);
            unsigned c3 = __builtin_nontemporal_load(epk + j + 48 + slot);
            u32x2 d0 = *(const u32x2*)(zb + (c0 >> 9));
            u32x2 d1 = *(const u32x2*)(zb + (c1 >> 9));
            u32x2 d2 = *(const u32x2*)(zb + (c2 >> 9));
            u32x2 d3 = *(const u32x2*)(zb + (c3 >> 9));
            float v0 = q2f<0>(c0), v1 = q2f<0>(c1);
            float v2 = q2f<0>(c2), v3 = q2f<0>(c3);
            f32x2 vv0 = {v0, v0}, vv1 = {v1, v1};
            f32x2 vv2 = {v2, v2}, vv3 = {v3, v3};
            FMA8P(vv0, d0)
            FMA8P(vv1, d1)
            FMA8P(vv2, d2)
            FMA8P(vv3, d3)
        }
        if (j < e) {  // 33..64 edges left: one 64-slot predicated burst
            int i0 = min(j + slot, e - 1);
            int i1 = min(j + 16 + slot, e - 1);
            int i2 = min(j + 32 + slot, e - 1);
            int i3 = min(j + 48 + slot, e - 1);
            unsigned c0 = __builtin_nontemporal_load(epk + i0);
            unsigned c1 = __builtin_nontemporal_load(epk + i1);
            unsigned c2 = __builtin_nontemporal_load(epk + i2);
            unsigned c3 = __builtin_nontemporal_load(epk + i3);
            u32x2 d0 = *(const u32x2*)(zb + (c0 >> 9));
            u32x2 d1 = *(const u32x2*)(zb + (c1 >> 9));
            u32x2 d2 = *(const u32x2*)(zb + (c2 >> 9));
            u32x2 d3 = *(const u32x2*)(zb + (c3 >> 9));
            float v0 = (j + slot < e) ? q2f<0>(c0) : 0.f;
            float v1 = (j + 16 + slot < e) ? q2f<0>(c1) : 0.f;
            float v2 = (j + 32 + slot < e) ? q2f<0>(c2) : 0.f;
            float v3 = (j + 48 + slot < e) ? q2f<0>(c3) : 0.f;
            f32x2 vv0 = {v0, v0}, vv1 = {v1, v1};
            f32x2 vv2 = {v2, v2}, vv3 = {v3, v3};
            FMA8P(vv0, d0)
            FMA8P(vv1, d1)
            FMA8P(vv2, d2)
            FMA8P(vv3, d3)
        }
    }

    // epilogue-only setup: issued after the gather chain is in flight.
    // dim mapping after split rounds (bits 2,3,4); lanes l and l^32 dup.
    int dimL = dim4 * 8 + ((lane >> 2) & 1) * 4 + ((lane >> 3) & 1) * 2 +
               ((lane >> 4) & 1);
    int oidx = hofs + dimL;
    float bv = bias[oidx];
    float ra = 0.f, rb = 0.f;
    if (L3) {
        ra = __builtin_nontemporal_load(xa + (size_t)row * 64 + oidx);
        rb = __builtin_nontemporal_load(xb + (size_t)row * 64 + oidx);
    }

    // re-extract scalars (constant indices -> stays in registers)
    float a[8];
#pragma unroll
    for (int k = 0; k < 8; ++k) a[k] = a2[k >> 1][k & 1];

    // recursive-halving reduce over 16 slots with dim-splitting (3 rounds),
    // then a plain add across the lane^32 halves (dims duplicated).
    float r4[4];
    {
        bool h = (lane & 4) != 0;
#pragma unroll
        for (int k = 0; k < 4; ++k) {
            float keep = h ? a[4 + k] : a[k];
            float give = h ? a[k] : a[4 + k];
            r4[k] = keep + __shfl_xor(give, 4, 64);
        }
    }
    float r2[2];
    {
        bool h = (lane & 8) != 0;
#pragma unroll
        for (int k = 0; k < 2; ++k) {
            float keep = h ? r2[0] : r2[0];  // placeholder, replaced below
            (void)keep;
            float kp = h ? r4[2 + k] : r4[k];
            float gv = h ? r4[k] : r4[2 + k];
            r2[k] = kp + __shfl_xor(gv, 8, 64);
        }
    }
    float r1;
    {
        bool h = (lane & 16) != 0;
        float kp = h ? r2[1] : r2[0];
        float gv = h ? r2[0] : r2[1];
        r1 = kp + __shfl_xor(gv, 16, 64);
    }
    float tot = r1 + __shfl_xor(r1, 32, 64);

    float o = fmaxf(fmaf(tot, 0.0625f, bv), 0.f);
    if (L3) o += ra + rb;
    if (lane < 32)  // lanes 32-63 hold duplicates
        xout[(size_t)row * 64 + oidx] = o;
}

// Pool: batch sorted -> run-length accumulate NODE_CHUNK nodes per wave, one
// atomicAdd per segment boundary per lane. h already = x1+x2+x3.
#define NODE_CHUNK 16
__global__ void pool_k(const float* __restrict__ h, const int* __restrict__ batch,
                       float* __restrict__ sums, int* __restrict__ cnts, int n) {
    int lane = threadIdx.x & 63;
    int w = (blockIdx.x * blockDim.x + threadIdx.x) >> 6;
    int node0 = w * NODE_CHUNK;
    if (node0 >= n) return;
    int cur = batch[node0];
    float acc = 0.f;
    int cnt = 0;
    int end = min(node0 + NODE_CHUNK, n);
    for (int nd = node0; nd < end; ++nd) {
        int bg = batch[nd];  // wave-uniform
        if (bg != cur) {
            atomicAdd(&sums[(size_t)cur * 64 + lane], acc);
            if (lane == 0) atomicAdd(&cnts[cur], cnt);
            acc = 0.f;
            cnt = 0;
            cur = bg;
        }
        acc += h[(size_t)nd * 64 + lane];
        cnt++;
    }
    atomicAdd(&sums[(size_t)cur * 64 + lane], acc);
    if (lane == 0) atomicAdd(&cnts[cur], cnt);
}

// Head: pooled = sums/(3*cnt); out = softmax(pooled @ Wl + bl). Wave per graph.
__global__ void final_k(const float* __restrict__ sums, const int* __restrict__ cnts,
                        const float* __restrict__ Wl, const float* __restrict__ bl,
                        float* __restrict__ out, int G) {
    int lane = threadIdx.x & 63;
    int g = (blockIdx.x * blockDim.x + threadIdx.x) >> 6;
    if (g >= G) return;
    float c = (float)max(cnts[g], 1);
    float s = sums[(size_t)g * 64 + lane] / (3.f * c);
    float y = (lane < 10) ? bl[lane] : -1e30f;
    for (int k = 0; k < 64; ++k) {
        float sk = __shfl(s, k, 64);
        if (lane < 10) y = fmaf(sk, Wl[k * 10 + lane], y);
    }
    float m = y;
#pragma unroll
    for (int off = 8; off; off >>= 1) m = fmaxf(m, __shfl_xor(m, off, 16));
    float ey = (lane < 10) ? __expf(y - m) : 0.f;
    float sm = ey;
#pragma unroll
    for (int off = 8; off; off >>= 1) sm += __shfl_xor(sm, off, 16);
    if (lane < 10) out[(size_t)g * 10 + lane] = ey / sm;
}

extern "C" void kernel_launch(void* const* d_in, const int* in_sizes, int n_in,
                              void* d_out, int out_size, void* d_ws, size_t ws_size,
                              hipStream_t stream) {
    const float* x = (const float*)d_in[0];
    const int* rows = (const int*)d_in[1];
    const int* cols = (const int*)d_in[2];
    const float* vals = (const float*)d_in[3];
    const int* batch = (const int*)d_in[4];
    const float* W1 = (const float*)d_in[5];
    const float* b1 = (const float*)d_in[6];
    const float* W2 = (const float*)d_in[7];
    const float* b2 = (const float*)d_in[8];
    const float* W3 = (const float*)d_in[9];
    const float* b3 = (const float*)d_in[10];
    const float* Wl = (const float*)d_in[11];
    const float* bl = (const float*)d_in[12];
    float* out = (float*)d_out;

    const int N = in_sizes[4];   // n_nodes (<= 131072)
    const int E = in_sizes[1];   // n_edges
    const int G = out_size / 10; // n_graphs
    const int K = (N + BROWS - 1) >> BSHIFT;

    char* p = (char*)d_ws;
    size_t off = 0;
    auto alloc = [&](size_t bytes) -> void* {
        off = (off + 255) & ~(size_t)255;
        void* r = (void*)(p + off);
        off += bytes;
        return r;
    };
    size_t featF = (size_t)N * 64 * 4;
    int* bhist = (int*)alloc(MAXK * 4);
    int* bstart = (int*)alloc((MAXK + 1) * 4);
    int* bcur = (int*)alloc(MAXK * 16 * 4);
    int* rp = (int*)alloc((size_t)(N + 2) * 4);
    // pk (bucketed, pre-sort) is dead after sort_k; alias with h (written
    // only by the layer-3 spmm, far after sort_k).
    void* regP = alloc((size_t)E * 8 > featF ? (size_t)E * 8 : featF);
    unsigned* epk = (unsigned*)alloc((size_t)E * 4);  // packed sorted edges
    unsigned char* ZqA_lo = (unsigned char*)alloc((size_t)N * 32);
    unsigned char* ZqA_hi = (unsigned char*)alloc((size_t)N * 32);
    unsigned char* ZqB_lo = (unsigned char*)alloc((size_t)N * 32);
    unsigned char* ZqB_hi = (unsigned char*)alloc((size_t)N * 32);
    float* x1 = (float*)alloc(featF);
    float* x2 = (float*)alloc(featF);
    float* sums = (float*)alloc((size_t)G * 64 * 4);
    int* cnts = (int*)alloc((size_t)G * 4);

    unsigned long long* pk = (unsigned long long*)regP;
    float* h = (float*)regP;

    (void)hipMemsetAsync(bhist, 0, MAXK * 4, stream);

    int cb = (E + CHUNK - 1) / CHUNK;
    bhist_k<<<cb, 512, 0, stream>>>(rows, bhist, sums, cnts, E, G);
    bscan_k<<<1, MAXK, 0, stream>>>(bhist, bstart, bcur, rp, K, E, N);
    binpass_k<<<cb, 512, 0, stream>>>(rows, cols, vals, bcur, pk, E);
    sort_k<<<K, 512, 0, stream>>>(bstart, pk, rp, epk, N);

    int rb = (N + 3) / 4;  // wave-per-row blocks
    dense5_k<<<rb, 256, 0, stream>>>(x, W1, ZqA_lo, ZqA_hi, N);
    spmm16_k<0><<<rb, 256, 0, stream>>>(rp, epk, ZqA_lo, b1, nullptr, nullptr, x1, N, 0);
    spmm16_k<0><<<rb, 256, 0, stream>>>(rp, epk, ZqA_hi, b1, nullptr, nullptr, x1, N, 32);
    dense64_k<<<512, 256, 0, stream>>>(x1, W2, ZqB_lo, ZqB_hi, N);
    spmm16_k<0><<<rb, 256, 0, stream>>>(rp, epk, ZqB_lo, b2, nullptr, nullptr, x2, N, 0);
    spmm16_k<0><<<rb, 256, 0, stream>>>(rp, epk, ZqB_hi, b2, nullptr, nullptr, x2, N, 32);
    dense64_k<<<512, 256, 0, stream>>>(x2, W3, ZqA_lo, ZqA_hi, N);
    spmm16_k<1><<<rb, 256, 0, stream>>>(rp, epk, ZqA_lo, b3, x1, x2, h, N, 0);
    spmm16_k<1><<<rb, 256, 0, stream>>>(rp, epk, ZqA_hi, b3, x1, x2, h, N, 32);

    int pw = (N + NODE_CHUNK - 1) / NODE_CHUNK;
    pool_k<<<(pw + 3) / 4, 256, 0, stream>>>(h, batch, sums, cnts, N);
    final_k<<<(G + 3) / 4, 256, 0, stream>>>(sums, cnts, Wl, bl, out, G);
}

// Round 13
// 361.483 us; speedup vs baseline: 1.2494x; 1.2494x over previous
//
#include <hip/hip_runtime.h>

// GCN3: 3x (COO spmm -> Linear(64) -> ReLU), segment-mean pool, softmax head.
// relu(spmm(X)@W + b) == relu(spmm(X@W) + b): dense transform first, then
// PULL-spmm from fp8 Z (e4m3, 64B/row). Edge record 4B: (col<<14)|fp8(val*16)
// (col pre-scaled so gather byte-offset is just rec>>8).
// spmm v11 (reverted from v12 split): deg-ADAPTIVE single burst per row;
// deg<=32 -> 32-slot predicated burst, else 64-slot; ONE serial memory round
// per row. v12 ERRATA: splitting Z into 2 L2-resident halves cut traffic but
// DOUBLED total wave count at fixed per-wave chain latency -> pair 77us vs
// 46.6. spmm duration = lifetime x waves / parallelism, not bytes.
// CSR build v13: BSHIFT 9->8 (256-row buckets, K~392 blocks). v12's profile
// exposed sort_k at 44us / occupancy 12.7% / K=196 blocks < 256 CUs -- pure
// parallelism starvation. 2x blocks halves per-block serial work.
// DO NOT replace build with direct global scatter (v9 ERRATA): 4B scatter
// lines fed from multiple XCDs = 16x write amplification (measured 195MB for
// 12.8MB); binpass guarantees every epk line is produced by ONE CU.
// dense64: MFMA 16x16x32 bf16, W staged in LDS per block.

#define BSHIFT 8
#define BROWS  (1 << BSHIFT)   // 256 rows per bucket
#define MAXK   512             // supports N <= 131072
#define CHUNK  6144            // edges per binpass/bhist block

typedef float f32x2 __attribute__((ext_vector_type(2)));
typedef float f32x4 __attribute__((ext_vector_type(4)));
typedef unsigned u32x4 __attribute__((ext_vector_type(4)));
typedef short bf16x8 __attribute__((ext_vector_type(8)));

__device__ inline unsigned char f2q(float f) {  // fp8 e4m3 RNE (saturating)
    unsigned p = __builtin_amdgcn_cvt_pk_fp8_f32(f, f, 0u, false);
    return (unsigned char)(p & 0xffu);
}
template <int SEL>
__device__ inline float q2f(unsigned q) {  // byte-select fp8->f32 (SEL = ICE)
    return __builtin_amdgcn_cvt_f32_fp8(q, SEL);
}
template <int HI>  // 2 fp8 (bytes 2*HI, 2*HI+1) -> 2 f32, one instr
__device__ inline f32x2 q2f2(unsigned q) {
#if __has_builtin(__builtin_amdgcn_cvt_pk_f32_fp8)
    return __builtin_amdgcn_cvt_pk_f32_fp8(q, HI != 0);
#else
    f32x2 r;
    r.x = q2f<2 * HI>(q);
    r.y = q2f<2 * HI + 1>(q);
    return r;
#endif
}

// pack 8 f32 (k ascending: lo.x..lo.w, hi.x..hi.w) -> bf16x8, RNE
__device__ inline bf16x8 pack_bf8(f32x4 lo, f32x4 hi) {
    union { u32x4 u; bf16x8 h; } r;
    asm("v_cvt_pk_bf16_f32 %0, %1, %2" : "=v"(r.u.x) : "v"(lo.x), "v"(lo.y));
    asm("v_cvt_pk_bf16_f32 %0, %1, %2" : "=v"(r.u.y) : "v"(lo.z), "v"(lo.w));
    asm("v_cvt_pk_bf16_f32 %0, %1, %2" : "=v"(r.u.z) : "v"(hi.x), "v"(hi.y));
    asm("v_cvt_pk_bf16_f32 %0, %1, %2" : "=v"(r.u.w) : "v"(hi.z), "v"(hi.w));
    return r.h;
}

// Per-block LDS histogram of bucket ids -> global bucket counts.
// Also zeroes the pool buffers (sums/cnts), grid-strided.
__global__ __launch_bounds__(512) void bhist_k(const int* __restrict__ rows,
                                               int* __restrict__ bhist,
                                               float* __restrict__ sums,
                                               int* __restrict__ cnts,
                                               int E, int G) {
    __shared__ int h[MAXK];
    int tx = threadIdx.x;
    h[tx] = 0;
    int gstep = gridDim.x * 512, gid = blockIdx.x * 512 + tx;
    f32x4* s4 = (f32x4*)sums;
    for (int i = gid; i < G * 16; i += gstep) s4[i] = 0;
    for (int i = gid; i < G; i += gstep) cnts[i] = 0;
    __syncthreads();
    int e0 = blockIdx.x * CHUNK, ee = min(e0 + CHUNK, E);
    for (int e = e0 + tx; e < ee; e += 512)
        atomicAdd(&h[rows[e] >> BSHIFT], 1);
    __syncthreads();
    if (h[tx]) atomicAdd(&bhist[tx], h[tx]);
}

// Exclusive scan of bucket counts (single block); init padded cursors; rp[N]=E.
__global__ __launch_bounds__(MAXK) void bscan_k(const int* __restrict__ bhist,
                                                int* __restrict__ bstart,
                                                int* __restrict__ bcur,
                                                int* __restrict__ rp,
                                                int K, int E, int N) {
    __shared__ int s[MAXK];
    int tx = threadIdx.x;
    int v = (tx < K) ? bhist[tx] : 0;
    s[tx] = v;
    __syncthreads();
    for (int off = 1; off < MAXK; off <<= 1) {
        int t = (tx >= off) ? s[tx - off] : 0;
        __syncthreads();
        s[tx] += t;
        __syncthreads();
    }
    if (tx < K) {
        bstart[tx] = s[tx] - v;
        bcur[tx * 16] = s[tx] - v;  // 1 cursor per 64B line
    }
    if (tx == K - 1) bstart[K] = E;
    if (tx == 0) rp[N] = E;
}

// Bin edges by 256-row bucket, staged in LDS so global writes are single-CU
// bursts. Record (u64): lo32=(col<<8)|(row&255), hi32=val bits.
__global__ __launch_bounds__(512) void binpass_k(
    const int* __restrict__ rows, const int* __restrict__ cols,
    const float* __restrict__ vals, int* __restrict__ bcur,
    unsigned long long* __restrict__ pk, int E) {
    __shared__ int h[MAXK], base[MAXK], gbase[MAXK], lcnt[MAXK];
    __shared__ unsigned long long st[CHUNK];  // 48 KB (+8KB tables = 56KB)
    int tx = threadIdx.x;
    h[tx] = 0;
    __syncthreads();
    int e0 = blockIdx.x * CHUNK, ee = min(e0 + CHUNK, E);
    for (int e = e0 + tx; e < ee; e += 512)
        atomicAdd(&h[rows[e] >> BSHIFT], 1);
    __syncthreads();
    int v = h[tx];
    lcnt[tx] = v;  // scan buffer
    __syncthreads();
    for (int off = 1; off < MAXK; off <<= 1) {
        int t = (tx >= off) ? lcnt[tx - off] : 0;
        __syncthreads();
        lcnt[tx] += t;
        __syncthreads();
    }
    base[tx] = lcnt[tx] - v;
    if (v) gbase[tx] = atomicAdd(&bcur[tx * 16], v);
    __syncthreads();
    lcnt[tx] = 0;
    __syncthreads();
    for (int e = e0 + tx; e < ee; e += 512) {
        int r = rows[e];
        int c = cols[e];
        float vv = vals[e];
        int b = r >> BSHIFT;
        int p = base[b] + atomicAdd(&lcnt[b], 1);
        unsigned lo = ((unsigned)c << BSHIFT) | (unsigned)(r & (BROWS - 1));
        st[p] = (unsigned long long)lo
              | ((unsigned long long)(unsigned)__float_as_int(vv) << 32);
    }
    __syncthreads();
    // flush contiguous per-bucket runs, wave-parallel.
    int lane = tx & 63, wid = tx >> 6;
    for (int b = wid; b < MAXK; b += 8) {
        int cnt = h[b];
        if (!cnt) continue;
        int lb = base[b], gb = gbase[b];
        for (int i = lane; i < cnt; i += 64)
            __builtin_nontemporal_store(st[lb + i], &pk[gb + i]);
    }
}

// Per-bucket counting sort: one block per 256-row bucket (K~2x CU count ->
// v13 fixes v12-exposed 12.7% occupancy). LDS hist, scan -> rp, local
// scatter into the bucket's contiguous epk window. CACHED loads/stores
// (sub-line scatter within ONE block's window: single-CU line production).
// Output record (4B): (col << 14) | fp8(val * 16).
__global__ __launch_bounds__(512) void sort_k(
    const int* __restrict__ bstart, const unsigned long long* __restrict__ pk,
    int* __restrict__ rp, unsigned* __restrict__ epk, int n) {
    __shared__ int hist[BROWS], cur[BROWS];
    int tx = threadIdx.x;
    int b = blockIdx.x;
    int row0 = b << BSHIFT;
    int s = bstart[b], e = bstart[b + 1];
    if (tx < BROWS) hist[tx] = 0;
    __syncthreads();
    for (int j = s + tx; j < e; j += 512) {
        unsigned lo = (unsigned)pk[j];
        atomicAdd(&hist[lo & (BROWS - 1)], 1);
    }
    __syncthreads();
    int v = (tx < BROWS) ? hist[tx] : 0;
    for (int off = 1; off < BROWS; off <<= 1) {
        int t = (tx >= off && tx < BROWS) ? hist[tx - off] : 0;
        __syncthreads();
        if (tx < BROWS) hist[tx] += t;
        __syncthreads();
    }
    if (tx < BROWS) {
        int excl = hist[tx] - v;
        cur[tx] = excl;
        if (row0 + tx < n) rp[row0 + tx] = s + excl;
    }
    __syncthreads();
    for (int j = s + tx; j < e; j += 512) {
        unsigned long long rec = pk[j];
        unsigned lo = (unsigned)rec;
        float vv = __int_as_float((int)(unsigned)(rec >> 32));
        int r = (int)(lo & (BROWS - 1));
        int q = atomicAdd(&cur[r], 1);
        epk[s + q] = ((lo >> BSHIFT) << 14) | (unsigned)f2q(vv * 16.f);
    }
}

// Zq = fp8(X @ W1), X:[n,5]. Wave per row, lane = out dim.
__global__ __launch_bounds__(256) void dense5_k(
    const float* __restrict__ X, const float* __restrict__ W,
    unsigned char* __restrict__ Zq, int n) {
    int lane = threadIdx.x & 63;
    int row = (blockIdx.x * blockDim.x + threadIdx.x) >> 6;
    if (row >= n) return;
    float w0 = W[lane], w1 = W[64 + lane], w2 = W[128 + lane],
          w3 = W[192 + lane], w4 = W[256 + lane];
    float xv = (lane < 5) ? X[(size_t)row * 5 + lane] : 0.f;
    float y = __shfl(xv, 0, 64) * w0;
    y = fmaf(__shfl(xv, 1, 64), w1, y);
    y = fmaf(__shfl(xv, 2, 64), w2, y);
    y = fmaf(__shfl(xv, 3, 64), w3, y);
    y = fmaf(__shfl(xv, 4, 64), w4, y);
    Zq[(size_t)row * 64 + lane] = f2q(y);
}

// dense64: Zq = fp8(X @ W) via mfma_f32_16x16x32_bf16. W staged into LDS
// coalesced once per block. LDS stride 65 -> conflict-free fragment reads.
// Wave = 16-row tile x 64 cols; frag (c,m) holds B[k=32m+8lk+i][col=16c+l15].
__global__ __launch_bounds__(256, 4) void dense64_k(
    const float* __restrict__ X, const float* __restrict__ W,
    unsigned char* __restrict__ Zq, int n) {
    __shared__ float wlds[64 * 65];
    int tx = threadIdx.x;
    int lane = tx & 63, wid = tx >> 6;
    int l15 = lane & 15, lk = lane >> 4;
#pragma unroll
    for (int i = 0; i < 16; ++i) {
        int idx = i * 256 + tx;              // coalesced: 1KB per instr
        wlds[(idx >> 6) * 65 + (idx & 63)] = W[idx];
    }
    __syncthreads();
    bf16x8 bw[4][2];
#pragma unroll
    for (int c = 0; c < 4; ++c) {
#pragma unroll
        for (int m = 0; m < 2; ++m) {
            const float* wp = wlds + (32 * m + 8 * lk) * 65 + 16 * c + l15;
            f32x4 lo, hi;
            lo.x = wp[0];       lo.y = wp[65];      lo.z = wp[130];  lo.w = wp[195];
            hi.x = wp[260];     hi.y = wp[325];     hi.z = wp[390];  hi.w = wp[455];
            bw[c][m] = pack_bf8(lo, hi);
        }
    }
    int nt = (n + 15) >> 4;
    int nwv = (int)(gridDim.x * 4);
    for (int t = blockIdx.x * 4 + wid; t < nt; t += nwv) {
        int rowb = t << 4;
        int ar = min(rowb + l15, n - 1);  // clamped A row (stores guarded)
        const float* xr = X + (size_t)ar * 64 + 8 * lk;
        f32x4 a0 = *(const f32x4*)(xr);
        f32x4 a1 = *(const f32x4*)(xr + 4);
        f32x4 a2 = *(const f32x4*)(xr + 32);
        f32x4 a3 = *(const f32x4*)(xr + 36);
        bf16x8 A0 = pack_bf8(a0, a1);
        bf16x8 A1 = pack_bf8(a2, a3);
        f32x4 acc0 = 0, acc1 = 0, acc2 = 0, acc3 = 0;
        acc0 = __builtin_amdgcn_mfma_f32_16x16x32_bf16(A0, bw[0][0], acc0, 0, 0, 0);
        acc1 = __builtin_amdgcn_mfma_f32_16x16x32_bf16(A0, bw[1][0], acc1, 0, 0, 0);
        acc2 = __builtin_amdgcn_mfma_f32_16x16x32_bf16(A0, bw[2][0], acc2, 0, 0, 0);
        acc3 = __builtin_amdgcn_mfma_f32_16x16x32_bf16(A0, bw[3][0], acc3, 0, 0, 0);
        acc0 = __builtin_amdgcn_mfma_f32_16x16x32_bf16(A1, bw[0][1], acc0, 0, 0, 0);
        acc1 = __builtin_amdgcn_mfma_f32_16x16x32_bf16(A1, bw[1][1], acc1, 0, 0, 0);
        acc2 = __builtin_amdgcn_mfma_f32_16x16x32_bf16(A1, bw[2][1], acc2, 0, 0, 0);
        acc3 = __builtin_amdgcn_mfma_f32_16x16x32_bf16(A1, bw[3][1], acc3, 0, 0, 0);
#pragma unroll
        for (int j = 0; j < 4; ++j) {
            int r = rowb + 4 * lk + j;
            if (r < n) {
                unsigned char* zp = Zq + (size_t)r * 64 + l15;
                zp[0]  = f2q(acc0[j]);
                zp[16] = f2q(acc1[j]);
                zp[32] = f2q(acc2[j]);
                zp[48] = f2q(acc3[j]);
            }
        }
    }
}

// Packed core: one edge's 16B Zq chunk into a2[0..7] (f32x2 = 2 dims each).
// 8 cvt_pk + 8 pk_fma per edge.
#define FMA16P(vv2, d)                                                         \
    a2[0] += (vv2) * q2f2<0>((d).x);                                           \
    a2[1] += (vv2) * q2f2<1>((d).x);                                           \
    a2[2] += (vv2) * q2f2<0>((d).y);                                           \
    a2[3] += (vv2) * q2f2<1>((d).y);                                           \
    a2[4] += (vv2) * q2f2<0>((d).z);                                           \
    a2[5] += (vv2) * q2f2<1>((d).z);                                           \
    a2[6] += (vv2) * q2f2<0>((d).w);                                           \
    a2[7] += (vv2) * q2f2<1>((d).w);

// spmm v11: wave per row; 16 edge-slots (lane>>2) x 4 dim-lanes (lane&3).
// Deg-adaptive single predicated burst (32 or 64 slots, wave-uniform
// branch); idx clamped to e-1, v masked 0. Zq NaN-free (cvt saturates).
template <int L3>
__global__ __launch_bounds__(256, 8) void spmm16_k(
    const int* __restrict__ rp, const unsigned* __restrict__ epk,
    const unsigned char* __restrict__ Zq, const float* __restrict__ bias,
    const float* __restrict__ xa, const float* __restrict__ xb,
    float* __restrict__ xout, int n) {
    int lane = threadIdx.x & 63;
    int dim4 = lane & 3, slot = lane >> 2;
    int row = __builtin_amdgcn_readfirstlane(
        (int)((blockIdx.x * blockDim.x + threadIdx.x) >> 6));
    if (row >= n) return;
    int s = rp[row], e = rp[row + 1];    // scalar loads (wave-uniform row)
    const unsigned char* zb = Zq + (dim4 << 4);

    f32x2 a2[8];
#pragma unroll
    for (int k = 0; k < 8; ++k) a2[k] = 0;

    if (e - s <= 32) {  // ~55% of rows (Poisson(32)): 32-slot burst
        int i0 = min(s + slot, e - 1);
        int i1 = min(s + 16 + slot, e - 1);
        unsigned c0 = __builtin_nontemporal_load(epk + i0);
        unsigned c1 = __builtin_nontemporal_load(epk + i1);
        u32x4 d0 = *(const u32x4*)(zb + (c0 >> 8));  // c>>8 = col*64
        u32x4 d1 = *(const u32x4*)(zb + (c1 >> 8));
        float v0 = (s + slot < e) ? q2f<0>(c0) : 0.f;
        float v1 = (s + 16 + slot < e) ? q2f<0>(c1) : 0.f;
        f32x2 vv0 = {v0, v0}, vv1 = {v1, v1};
        FMA16P(vv0, d0)
        FMA16P(vv1, d1)
    } else {
        int j = s;
        for (; j + 64 <= e; j += 64) {  // rare (P ~ 6e-7): full 64-bursts
            unsigned c0 = __builtin_nontemporal_load(epk + j + slot);
            unsigned c1 = __builtin_nontemporal_load(epk + j + 16 + slot);
            unsigned c2 = __builtin_nontemporal_load(epk + j + 32 + slot);
            unsigned c3 = __builtin_nontemporal_load(epk + j + 48 + slot);
            u32x4 d0 = *(const u32x4*)(zb + (c0 >> 8));
            u32x4 d1 = *(const u32x4*)(zb + (c1 >> 8));
            u32x4 d2 = *(const u32x4*)(zb + (c2 >> 8));
            u32x4 d3 = *(const u32x4*)(zb + (c3 >> 8));
            float v0 = q2f<0>(c0), v1 = q2f<0>(c1);
            float v2 = q2f<0>(c2), v3 = q2f<0>(c3);
            f32x2 vv0 = {v0, v0}, vv1 = {v1, v1};
            f32x2 vv2 = {v2, v2}, vv3 = {v3, v3};
            FMA16P(vv0, d0)
            FMA16P(vv1, d1)
            FMA16P(vv2, d2)
            FMA16P(vv3, d3)
        }
        if (j < e) {  // 33..64 edges left: one 64-slot predicated burst
            int i0 = min(j + slot, e - 1);
            int i1 = min(j + 16 + slot, e - 1);
            int i2 = min(j + 32 + slot, e - 1);
            int i3 = min(j + 48 + slot, e - 1);
            unsigned c0 = __builtin_nontemporal_load(epk + i0);
            unsigned c1 = __builtin_nontemporal_load(epk + i1);
            unsigned c2 = __builtin_nontemporal_load(epk + i2);
            unsigned c3 = __builtin_nontemporal_load(epk + i3);
            u32x4 d0 = *(const u32x4*)(zb + (c0 >> 8));
            u32x4 d1 = *(const u32x4*)(zb + (c1 >> 8));
            u32x4 d2 = *(const u32x4*)(zb + (c2 >> 8));
            u32x4 d3 = *(const u32x4*)(zb + (c3 >> 8));
            float v0 = (j + slot < e) ? q2f<0>(c0) : 0.f;
            float v1 = (j + 16 + slot < e) ? q2f<0>(c1) : 0.f;
            float v2 = (j + 32 + slot < e) ? q2f<0>(c2) : 0.f;
            float v3 = (j + 48 + slot < e) ? q2f<0>(c3) : 0.f;
            f32x2 vv0 = {v0, v0}, vv1 = {v1, v1};
            f32x2 vv2 = {v2, v2}, vv3 = {v3, v3};
            FMA16P(vv0, d0)
            FMA16P(vv1, d1)
            FMA16P(vv2, d2)
            FMA16P(vv3, d3)
        }
    }

    // epilogue-only setup: issued after the gather chain is in flight
    int dimL = dim4 * 16 + ((lane >> 2) & 1) * 8 + ((lane >> 3) & 1) * 4 +
               ((lane >> 4) & 1) * 2 + ((lane >> 5) & 1);
    float bv = bias[dimL];
    float ra = 0.f, rb = 0.f;
    if (L3) {
        ra = __builtin_nontemporal_load(xa + (size_t)row * 64 + dimL);
        rb = __builtin_nontemporal_load(xb + (size_t)row * 64 + dimL);
    }

    // re-extract scalars (constant indices -> stays in registers)
    float a[16];
#pragma unroll
    for (int k = 0; k < 16; ++k) a[k] = a2[k >> 1][k & 1];

    // recursive-halving reduce over 16 slots with dim-splitting:
    // each round keep half the dims, donate the other half to the partner.
    float r8[8];
    {
        bool h = (lane & 4) != 0;
#pragma unroll
        for (int k = 0; k < 8; ++k) {
            float keep = h ? a[8 + k] : a[k];
            float give = h ? a[k] : a[8 + k];
            r8[k] = keep + __shfl_xor(give, 4, 64);
        }
    }
    float r4[4];
    {
        bool h = (lane & 8) != 0;
#pragma unroll
        for (int k = 0; k < 4; ++k) {
            float keep = h ? r8[4 + k] : r8[k];
            float give = h ? r8[k] : r8[4 + k];
            r4[k] = keep + __shfl_xor(give, 8, 64);
        }
    }
    float r2[2];
    {
        bool h = (lane & 16) != 0;
#pragma unroll
        for (int k = 0; k < 2; ++k) {
            float keep = h ? r4[2 + k] : r4[k];
            float give = h ? r4[k] : r4[2 + k];
            r2[k] = keep + __shfl_xor(give, 16, 64);
        }
    }
    float tot;
    {
        bool h = (lane & 32) != 0;
        float keep = h ? r2[1] : r2[0];
        float give = h ? r2[0] : r2[1];
        tot = keep + __shfl_xor(give, 32, 64);
    }

    float o = fmaxf(fmaf(tot, 0.0625f, bv), 0.f);
    if (L3) o += ra + rb;
    xout[(size_t)row * 64 + dimL] = o;  // all 64 lanes store (256B/row)
}

// Pool: batch sorted -> run-length accumulate NODE_CHUNK nodes per wave, one
// atomicAdd per segment boundary per lane. h already = x1+x2+x3.
#define NODE_CHUNK 16
__global__ void pool_k(const float* __restrict__ h, const int* __restrict__ batch,
                       float* __restrict__ sums, int* __restrict__ cnts, int n) {
    int lane = threadIdx.x & 63;
    int w = (blockIdx.x * blockDim.x + threadIdx.x) >> 6;
    int node0 = w * NODE_CHUNK;
    if (node0 >= n) return;
    int cur = batch[node0];
    float acc = 0.f;
    int cnt = 0;
    int end = min(node0 + NODE_CHUNK, n);
    for (int nd = node0; nd < end; ++nd) {
        int bg = batch[nd];  // wave-uniform
        if (bg != cur) {
            atomicAdd(&sums[(size_t)cur * 64 + lane], acc);
            if (lane == 0) atomicAdd(&cnts[cur], cnt);
            acc = 0.f;
            cnt = 0;
            cur = bg;
        }
        acc += h[(size_t)nd * 64 + lane];
        cnt++;
    }
    atomicAdd(&sums[(size_t)cur * 64 + lane], acc);
    if (lane == 0) atomicAdd(&cnts[cur], cnt);
}

// Head: pooled = sums/(3*cnt); out = softmax(pooled @ Wl + bl). Wave per graph.
__global__ void final_k(const float* __restrict__ sums, const int* __restrict__ cnts,
                        const float* __restrict__ Wl, const float* __restrict__ bl,
                        float* __restrict__ out, int G) {
    int lane = threadIdx.x & 63;
    int g = (blockIdx.x * blockDim.x + threadIdx.x) >> 6;
    if (g >= G) return;
    float c = (float)max(cnts[g], 1);
    float s = sums[(size_t)g * 64 + lane] / (3.f * c);
    float y = (lane < 10) ? bl[lane] : -1e30f;
    for (int k = 0; k < 64; ++k) {
        float sk = __shfl(s, k, 64);
        if (lane < 10) y = fmaf(sk, Wl[k * 10 + lane], y);
    }
    float m = y;
#pragma unroll
    for (int off = 8; off; off >>= 1) m = fmaxf(m, __shfl_xor(m, off, 16));
    float ey = (lane < 10) ? __expf(y - m) : 0.f;
    float sm = ey;
#pragma unroll
    for (int off = 8; off; off >>= 1) sm += __shfl_xor(sm, off, 16);
    if (lane < 10) out[(size_t)g * 10 + lane] = ey / sm;
}

extern "C" void kernel_launch(void* const* d_in, const int* in_sizes, int n_in,
                              void* d_out, int out_size, void* d_ws, size_t ws_size,
                              hipStream_t stream) {
    const float* x = (const float*)d_in[0];
    const int* rows = (const int*)d_in[1];
    const int* cols = (const int*)d_in[2];
    const float* vals = (const float*)d_in[3];
    const int* batch = (const int*)d_in[4];
    const float* W1 = (const float*)d_in[5];
    const float* b1 = (const float*)d_in[6];
    const float* W2 = (const float*)d_in[7];
    const float* b2 = (const float*)d_in[8];
    const float* W3 = (const float*)d_in[9];
    const float* b3 = (const float*)d_in[10];
    const float* Wl = (const float*)d_in[11];
    const float* bl = (const float*)d_in[12];
    float* out = (float*)d_out;

    const int N = in_sizes[4];   // n_nodes (<= 131072)
    const int E = in_sizes[1];   // n_edges
    const int G = out_size / 10; // n_graphs
    const int K = (N + BROWS - 1) >> BSHIFT;

    char* p = (char*)d_ws;
    size_t off = 0;
    auto alloc = [&](size_t bytes) -> void* {
        off = (off + 255) & ~(size_t)255;
        void* r = (void*)(p + off);
        off += bytes;
        return r;
    };
    size_t featF = (size_t)N * 64 * 4;
    int* bhist = (int*)alloc(MAXK * 4);
    int* bstart = (int*)alloc((MAXK + 1) * 4);
    int* bcur = (int*)alloc(MAXK * 16 * 4);
    int* rp = (int*)alloc((size_t)(N + 2) * 4);
    // pk (bucketed, pre-sort) is dead after sort_k; alias with h (written
    // only by the layer-3 spmm, far after sort_k).
    void* regP = alloc((size_t)E * 8 > featF ? (size_t)E * 8 : featF);
    unsigned* epk = (unsigned*)alloc((size_t)E * 4);  // packed sorted edges
    unsigned char* ZqA = (unsigned char*)alloc((size_t)N * 64);
    unsigned char* ZqB = (unsigned char*)alloc((size_t)N * 64);
    float* x1 = (float*)alloc(featF);
    float* x2 = (float*)alloc(featF);
    float* sums = (float*)alloc((size_t)G * 64 * 4);
    int* cnts = (int*)alloc((size_t)G * 4);

    unsigned long long* pk = (unsigned long long*)regP;
    float* h = (float*)regP;

    (void)hipMemsetAsync(bhist, 0, MAXK * 4, stream);

    int cb = (E + CHUNK - 1) / CHUNK;
    bhist_k<<<cb, 512, 0, stream>>>(rows, bhist, sums, cnts, E, G);
    bscan_k<<<1, MAXK, 0, stream>>>(bhist, bstart, bcur, rp, K, E, N);
    binpass_k<<<cb, 512, 0, stream>>>(rows, cols, vals, bcur, pk, E);
    sort_k<<<K, 512, 0, stream>>>(bstart, pk, rp, epk, N);

    int rb = (N + 3) / 4;  // wave-per-row blocks
    dense5_k<<<rb, 256, 0, stream>>>(x, W1, ZqA, N);
    spmm16_k<0><<<rb, 256, 0, stream>>>(rp, epk, ZqA, b1, nullptr, nullptr, x1, N);
    dense64_k<<<512, 256, 0, stream>>>(x1, W2, ZqB, N);
    spmm16_k<0><<<rb, 256, 0, stream>>>(rp, epk, ZqB, b2, nullptr, nullptr, x2, N);
    dense64_k<<<512, 256, 0, stream>>>(x2, W3, ZqA, N);
    spmm16_k<1><<<rb, 256, 0, stream>>>(rp, epk, ZqA, b3, x1, x2, h, N);

    int pw = (N + NODE_CHUNK - 1) / NODE_CHUNK;
    pool_k<<<(pw + 3) / 4, 256, 0, stream>>>(h, batch, sums, cnts, N);
    final_k<<<(G + 3) / 4, 256, 0, stream>>>(sums, cnts, Wl, bl, out, G);
}

// Round 14
// 339.666 us; speedup vs baseline: 1.3297x; 1.0642x over previous
//
#include <hip/hip_runtime.h>

// GCN3: 3x (COO spmm -> Linear(64) -> ReLU), segment-mean pool, softmax head.
// relu(spmm(X)@W + b) == relu(spmm(X@W) + b): dense transform first, then
// PULL-spmm from fp8 Z (e4m3, 64B/row). Edge record 4B: (col<<14)|fp8(val*16)
// (col pre-scaled so gather byte-offset is just rec>>8).
// spmm v11: deg-ADAPTIVE single burst per row; deg<=32 -> 32-slot predicated
// burst, else 64-slot; ONE serial memory round per row (v8 invariant).
// v12 ERRATA: L2-resident Z halves cut traffic but doubled wave count at
// fixed chain latency -> slower. spmm duration = lifetime x waves, not bytes.
// CSR build v14 (BSHIFT 9 restored; v13's BSHIFT 8 cost binpass occupancy
// 3->2 blocks/CU, net zero): (a) sort_k 1024 threads/block -- its 44us was
// thread starvation (196 blocks x 8 waves = 2 waves/SIMD), not bucket size;
// (b) bhist_k pass ELIMINATED via fixed-capacity pk buckets (C = E/K + 4096,
// 32-sigma safe): binpass needs no precomputed bases, accumulates the global
// bucket histogram itself; bscan moved after binpass; tiny init_k replaces
// the full-E bhist pass.
// DO NOT replace build with direct global scatter (v9 ERRATA): 4B scatter
// lines fed from multiple XCDs = 16x write amplification (measured 195MB for
// 12.8MB); binpass guarantees every epk line is produced by ONE CU.
// dense64: MFMA 16x16x32 bf16, W staged in LDS per block.

#define BSHIFT 9
#define BROWS  (1 << BSHIFT)   // 512 rows per bucket
#define MAXK   256             // supports N <= 131072
#define CHUNK  6144            // edges per binpass block

typedef float f32x2 __attribute__((ext_vector_type(2)));
typedef float f32x4 __attribute__((ext_vector_type(4)));
typedef unsigned u32x4 __attribute__((ext_vector_type(4)));
typedef short bf16x8 __attribute__((ext_vector_type(8)));

__device__ inline unsigned char f2q(float f) {  // fp8 e4m3 RNE (saturating)
    unsigned p = __builtin_amdgcn_cvt_pk_fp8_f32(f, f, 0u, false);
    return (unsigned char)(p & 0xffu);
}
template <int SEL>
__device__ inline float q2f(unsigned q) {  // byte-select fp8->f32 (SEL = ICE)
    return __builtin_amdgcn_cvt_f32_fp8(q, SEL);
}
template <int HI>  // 2 fp8 (bytes 2*HI, 2*HI+1) -> 2 f32, one instr
__device__ inline f32x2 q2f2(unsigned q) {
#if __has_builtin(__builtin_amdgcn_cvt_pk_f32_fp8)
    return __builtin_amdgcn_cvt_pk_f32_fp8(q, HI != 0);
#else
    f32x2 r;
    r.x = q2f<2 * HI>(q);
    r.y = q2f<2 * HI + 1>(q);
    return r;
#endif
}

// pack 8 f32 (k ascending: lo.x..lo.w, hi.x..hi.w) -> bf16x8, RNE
__device__ inline bf16x8 pack_bf8(f32x4 lo, f32x4 hi) {
    union { u32x4 u; bf16x8 h; } r;
    asm("v_cvt_pk_bf16_f32 %0, %1, %2" : "=v"(r.u.x) : "v"(lo.x), "v"(lo.y));
    asm("v_cvt_pk_bf16_f32 %0, %1, %2" : "=v"(r.u.y) : "v"(lo.z), "v"(lo.w));
    asm("v_cvt_pk_bf16_f32 %0, %1, %2" : "=v"(r.u.z) : "v"(hi.x), "v"(hi.y));
    asm("v_cvt_pk_bf16_f32 %0, %1, %2" : "=v"(r.u.w) : "v"(hi.z), "v"(hi.w));
    return r.h;
}

// Tiny init: zero bhist, set fixed-capacity bucket cursors, zero pool bufs.
// Replaces the full-E bhist_k pass (v14).
__global__ __launch_bounds__(256) void init_k(int* __restrict__ bhist,
                                              int* __restrict__ bcur,
                                              float* __restrict__ sums,
                                              int* __restrict__ cnts,
                                              int K, int C, int G) {
    int gid = blockIdx.x * 256 + threadIdx.x, gstep = gridDim.x * 256;
    for (int i = gid; i < MAXK; i += gstep) bhist[i] = 0;
    for (int i = gid; i < K; i += gstep) bcur[i * 16] = i * C;
    f32x4* s4 = (f32x4*)sums;
    for (int i = gid; i < G * 16; i += gstep) s4[i] = 0;
    for (int i = gid; i < G; i += gstep) cnts[i] = 0;
}

// Bin edges by 512-row bucket into FIXED-CAPACITY pk regions ([b*C, ...)),
// staged in LDS so global writes are single-CU bursts. Also accumulates the
// global bucket histogram (replaces bhist_k).
// Record (u64): lo32=(col<<9)|(row&511), hi32=val bits.
__global__ __launch_bounds__(512) void binpass_k(
    const int* __restrict__ rows, const int* __restrict__ cols,
    const float* __restrict__ vals, int* __restrict__ bcur,
    int* __restrict__ bhist, unsigned long long* __restrict__ pk, int E) {
    __shared__ int h[MAXK], base[MAXK], gbase[MAXK], lcnt[MAXK];
    __shared__ unsigned long long st[CHUNK];  // 48 KB
    int tx = threadIdx.x;
    if (tx < MAXK) h[tx] = 0;
    __syncthreads();
    int e0 = blockIdx.x * CHUNK, ee = min(e0 + CHUNK, E);
    for (int e = e0 + tx; e < ee; e += 512)
        atomicAdd(&h[rows[e] >> BSHIFT], 1);
    __syncthreads();
    int v = (tx < MAXK) ? h[tx] : 0;
    if (tx < MAXK) {
        lcnt[tx] = v;  // scan buffer
        if (v) atomicAdd(&bhist[tx], v);  // global bucket histogram
    }
    __syncthreads();
    for (int off = 1; off < MAXK; off <<= 1) {
        int t = (tx >= off && tx < MAXK) ? lcnt[tx - off] : 0;
        __syncthreads();
        if (tx < MAXK) lcnt[tx] += t;
        __syncthreads();
    }
    if (tx < MAXK) {
        base[tx] = lcnt[tx] - v;
        if (v) gbase[tx] = atomicAdd(&bcur[tx * 16], v);
        lcnt[tx] = 0;
    }
    __syncthreads();
    for (int e = e0 + tx; e < ee; e += 512) {
        int r = rows[e];
        int c = cols[e];
        float vv = vals[e];
        int b = r >> BSHIFT;
        int p = base[b] + atomicAdd(&lcnt[b], 1);
        unsigned lo = ((unsigned)c << BSHIFT) | (unsigned)(r & (BROWS - 1));
        st[p] = (unsigned long long)lo
              | ((unsigned long long)(unsigned)__float_as_int(vv) << 32);
    }
    __syncthreads();
    // flush contiguous per-bucket runs, wave-parallel. NT safe: 64 lanes x 8B
    // = 512B contiguous per instruction (full lines covered).
    int lane = tx & 63, wid = tx >> 6;
    for (int b = wid; b < MAXK; b += 8) {
        int cnt = h[b];
        if (!cnt) continue;
        int lb = base[b], gb = gbase[b];
        for (int i = lane; i < cnt; i += 64)
            __builtin_nontemporal_store(st[lb + i], &pk[gb + i]);
    }
}

// Exclusive scan of bucket counts (single block, AFTER binpass); rp[N]=E.
__global__ __launch_bounds__(MAXK) void bscan_k(const int* __restrict__ bhist,
                                                int* __restrict__ bstart,
                                                int* __restrict__ rp,
                                                int K, int E, int N) {
    __shared__ int s[MAXK];
    int tx = threadIdx.x;
    int v = (tx < K) ? bhist[tx] : 0;
    s[tx] = v;
    __syncthreads();
    for (int off = 1; off < MAXK; off <<= 1) {
        int t = (tx >= off) ? s[tx - off] : 0;
        __syncthreads();
        s[tx] += t;
        __syncthreads();
    }
    if (tx < K) bstart[tx] = s[tx] - v;
    if (tx == K - 1) bstart[K] = E;
    if (tx == 0) rp[N] = E;
}

// Per-bucket counting sort: one 1024-thread block per bucket (v14: was 512
// threads -> 2 waves/SIMD thread starvation, 44us at 3% VALU). Window =
// fixed-capacity region [b*C, b*C + bhist[b]); output base = bstart[b].
// CACHED loads/stores (sub-line scatter within ONE block's window: single-CU
// line production, L2-local assembly -- v9-ERRATA-safe).
// Output record (4B): (col << 14) | fp8(val * 16).
__global__ __launch_bounds__(1024) void sort_k(
    const int* __restrict__ bstart, const int* __restrict__ bhist,
    const unsigned long long* __restrict__ pk,
    int* __restrict__ rp, unsigned* __restrict__ epk, int n, int C) {
    __shared__ int hist[BROWS], cur[BROWS];
    int tx = threadIdx.x;
    int b = blockIdx.x;
    int row0 = b << BSHIFT;
    int s = b * C;
    int e = s + bhist[b];
    int eb = bstart[b];
    if (tx < BROWS) hist[tx] = 0;
    __syncthreads();
    for (int j = s + tx; j < e; j += 1024) {
        unsigned lo = (unsigned)pk[j];
        atomicAdd(&hist[lo & (BROWS - 1)], 1);
    }
    __syncthreads();
    int v = (tx < BROWS) ? hist[tx] : 0;
    for (int off = 1; off < BROWS; off <<= 1) {
        int t = (tx >= off && tx < BROWS) ? hist[tx - off] : 0;
        __syncthreads();
        if (tx < BROWS) hist[tx] += t;
        __syncthreads();
    }
    if (tx < BROWS) {
        int excl = hist[tx] - v;
        cur[tx] = excl;
        if (row0 + tx < n) rp[row0 + tx] = eb + excl;
    }
    __syncthreads();
    for (int j = s + tx; j < e; j += 1024) {
        unsigned long long rec = pk[j];
        unsigned lo = (unsigned)rec;
        float vv = __int_as_float((int)(unsigned)(rec >> 32));
        int r = (int)(lo & (BROWS - 1));
        int q = atomicAdd(&cur[r], 1);
        epk[eb + q] = ((lo >> BSHIFT) << 14) | (unsigned)f2q(vv * 16.f);
    }
}

// Zq = fp8(X @ W1), X:[n,5]. Wave per row, lane = out dim.
__global__ __launch_bounds__(256) void dense5_k(
    const float* __restrict__ X, const float* __restrict__ W,
    unsigned char* __restrict__ Zq, int n) {
    int lane = threadIdx.x & 63;
    int row = (blockIdx.x * blockDim.x + threadIdx.x) >> 6;
    if (row >= n) return;
    float w0 = W[lane], w1 = W[64 + lane], w2 = W[128 + lane],
          w3 = W[192 + lane], w4 = W[256 + lane];
    float xv = (lane < 5) ? X[(size_t)row * 5 + lane] : 0.f;
    float y = __shfl(xv, 0, 64) * w0;
    y = fmaf(__shfl(xv, 1, 64), w1, y);
    y = fmaf(__shfl(xv, 2, 64), w2, y);
    y = fmaf(__shfl(xv, 3, 64), w3, y);
    y = fmaf(__shfl(xv, 4, 64), w4, y);
    Zq[(size_t)row * 64 + lane] = f2q(y);
}

// dense64: Zq = fp8(X @ W) via mfma_f32_16x16x32_bf16. W staged into LDS
// coalesced once per block. LDS stride 65 -> conflict-free fragment reads.
// Wave = 16-row tile x 64 cols; frag (c,m) holds B[k=32m+8lk+i][col=16c+l15].
__global__ __launch_bounds__(256, 4) void dense64_k(
    const float* __restrict__ X, const float* __restrict__ W,
    unsigned char* __restrict__ Zq, int n) {
    __shared__ float wlds[64 * 65];
    int tx = threadIdx.x;
    int lane = tx & 63, wid = tx >> 6;
    int l15 = lane & 15, lk = lane >> 4;
#pragma unroll
    for (int i = 0; i < 16; ++i) {
        int idx = i * 256 + tx;              // coalesced: 1KB per instr
        wlds[(idx >> 6) * 65 + (idx & 63)] = W[idx];
    }
    __syncthreads();
    bf16x8 bw[4][2];
#pragma unroll
    for (int c = 0; c < 4; ++c) {
#pragma unroll
        for (int m = 0; m < 2; ++m) {
            const float* wp = wlds + (32 * m + 8 * lk) * 65 + 16 * c + l15;
            f32x4 lo, hi;
            lo.x = wp[0];       lo.y = wp[65];      lo.z = wp[130];  lo.w = wp[195];
            hi.x = wp[260];     hi.y = wp[325];     hi.z = wp[390];  hi.w = wp[455];
            bw[c][m] = pack_bf8(lo, hi);
        }
    }
    int nt = (n + 15) >> 4;
    int nwv = (int)(gridDim.x * 4);
    for (int t = blockIdx.x * 4 + wid; t < nt; t += nwv) {
        int rowb = t << 4;
        int ar = min(rowb + l15, n - 1);  // clamped A row (stores guarded)
        const float* xr = X + (size_t)ar * 64 + 8 * lk;
        f32x4 a0 = *(const f32x4*)(xr);
        f32x4 a1 = *(const f32x4*)(xr + 4);
        f32x4 a2 = *(const f32x4*)(xr + 32);
        f32x4 a3 = *(const f32x4*)(xr + 36);
        bf16x8 A0 = pack_bf8(a0, a1);
        bf16x8 A1 = pack_bf8(a2, a3);
        f32x4 acc0 = 0, acc1 = 0, acc2 = 0, acc3 = 0;
        acc0 = __builtin_amdgcn_mfma_f32_16x16x32_bf16(A0, bw[0][0], acc0, 0, 0, 0);
        acc1 = __builtin_amdgcn_mfma_f32_16x16x32_bf16(A0, bw[1][0], acc1, 0, 0, 0);
        acc2 = __builtin_amdgcn_mfma_f32_16x16x32_bf16(A0, bw[2][0], acc2, 0, 0, 0);
        acc3 = __builtin_amdgcn_mfma_f32_16x16x32_bf16(A0, bw[3][0], acc3, 0, 0, 0);
        acc0 = __builtin_amdgcn_mfma_f32_16x16x32_bf16(A1, bw[0][1], acc0, 0, 0, 0);
        acc1 = __builtin_amdgcn_mfma_f32_16x16x32_bf16(A1, bw[1][1], acc1, 0, 0, 0);
        acc2 = __builtin_amdgcn_mfma_f32_16x16x32_bf16(A1, bw[2][1], acc2, 0, 0, 0);
        acc3 = __builtin_amdgcn_mfma_f32_16x16x32_bf16(A1, bw[3][1], acc3, 0, 0, 0);
#pragma unroll
        for (int j = 0; j < 4; ++j) {
            int r = rowb + 4 * lk + j;
            if (r < n) {
                unsigned char* zp = Zq + (size_t)r * 64 + l15;
                zp[0]  = f2q(acc0[j]);
                zp[16] = f2q(acc1[j]);
                zp[32] = f2q(acc2[j]);
                zp[48] = f2q(acc3[j]);
            }
        }
    }
}

// Packed core: one edge's 16B Zq chunk into a2[0..7] (f32x2 = 2 dims each).
// 8 cvt_pk + 8 pk_fma per edge.
#define FMA16P(vv2, d)                                                         \
    a2[0] += (vv2) * q2f2<0>((d).x);                                           \
    a2[1] += (vv2) * q2f2<1>((d).x);                                           \
    a2[2] += (vv2) * q2f2<0>((d).y);                                           \
    a2[3] += (vv2) * q2f2<1>((d).y);                                           \
    a2[4] += (vv2) * q2f2<0>((d).z);                                           \
    a2[5] += (vv2) * q2f2<1>((d).z);                                           \
    a2[6] += (vv2) * q2f2<0>((d).w);                                           \
    a2[7] += (vv2) * q2f2<1>((d).w);

// spmm v11: wave per row; 16 edge-slots (lane>>2) x 4 dim-lanes (lane&3).
// Deg-adaptive single predicated burst (32 or 64 slots, wave-uniform
// branch); idx clamped to e-1, v masked 0. Zq NaN-free (cvt saturates).
template <int L3>
__global__ __launch_bounds__(256, 8) void spmm16_k(
    const int* __restrict__ rp, const unsigned* __restrict__ epk,
    const unsigned char* __restrict__ Zq, const float* __restrict__ bias,
    const float* __restrict__ xa, const float* __restrict__ xb,
    float* __restrict__ xout, int n) {
    int lane = threadIdx.x & 63;
    int dim4 = lane & 3, slot = lane >> 2;
    int row = __builtin_amdgcn_readfirstlane(
        (int)((blockIdx.x * blockDim.x + threadIdx.x) >> 6));
    if (row >= n) return;
    int s = rp[row], e = rp[row + 1];    // scalar loads (wave-uniform row)
    const unsigned char* zb = Zq + (dim4 << 4);

    f32x2 a2[8];
#pragma unroll
    for (int k = 0; k < 8; ++k) a2[k] = 0;

    if (e - s <= 32) {  // ~55% of rows (Poisson(32)): 32-slot burst
        int i0 = min(s + slot, e - 1);
        int i1 = min(s + 16 + slot, e - 1);
        unsigned c0 = __builtin_nontemporal_load(epk + i0);
        unsigned c1 = __builtin_nontemporal_load(epk + i1);
        u32x4 d0 = *(const u32x4*)(zb + (c0 >> 8));  // c>>8 = col*64
        u32x4 d1 = *(const u32x4*)(zb + (c1 >> 8));
        float v0 = (s + slot < e) ? q2f<0>(c0) : 0.f;
        float v1 = (s + 16 + slot < e) ? q2f<0>(c1) : 0.f;
        f32x2 vv0 = {v0, v0}, vv1 = {v1, v1};
        FMA16P(vv0, d0)
        FMA16P(vv1, d1)
    } else {
        int j = s;
        for (; j + 64 <= e; j += 64) {  // rare (P ~ 6e-7): full 64-bursts
            unsigned c0 = __builtin_nontemporal_load(epk + j + slot);
            unsigned c1 = __builtin_nontemporal_load(epk + j + 16 + slot);
            unsigned c2 = __builtin_nontemporal_load(epk + j + 32 + slot);
            unsigned c3 = __builtin_nontemporal_load(epk + j + 48 + slot);
            u32x4 d0 = *(const u32x4*)(zb + (c0 >> 8));
            u32x4 d1 = *(const u32x4*)(zb + (c1 >> 8));
            u32x4 d2 = *(const u32x4*)(zb + (c2 >> 8));
            u32x4 d3 = *(const u32x4*)(zb + (c3 >> 8));
            float v0 = q2f<0>(c0), v1 = q2f<0>(c1);
            float v2 = q2f<0>(c2), v3 = q2f<0>(c3);
            f32x2 vv0 = {v0, v0}, vv1 = {v1, v1};
            f32x2 vv2 = {v2, v2}, vv3 = {v3, v3};
            FMA16P(vv0, d0)
            FMA16P(vv1, d1)
            FMA16P(vv2, d2)
            FMA16P(vv3, d3)
        }
        if (j < e) {  // 33..64 edges left: one 64-slot predicated burst
            int i0 = min(j + slot, e - 1);
            int i1 = min(j + 16 + slot, e - 1);
            int i2 = min(j + 32 + slot, e - 1);
            int i3 = min(j + 48 + slot, e - 1);
            unsigned c0 = __builtin_nontemporal_load(epk + i0);
            unsigned c1 = __builtin_nontemporal_load(epk + i1);
            unsigned c2 = __builtin_nontemporal_load(epk + i2);
            unsigned c3 = __builtin_nontemporal_load(epk + i3);
            u32x4 d0 = *(const u32x4*)(zb + (c0 >> 8));
            u32x4 d1 = *(const u32x4*)(zb + (c1 >> 8));
            u32x4 d2 = *(const u32x4*)(zb + (c2 >> 8));
            u32x4 d3 = *(const u32x4*)(zb + (c3 >> 8));
            float v0 = (j + slot < e) ? q2f<0>(c0) : 0.f;
            float v1 = (j + 16 + slot < e) ? q2f<0>(c1) : 0.f;
            float v2 = (j + 32 + slot < e) ? q2f<0>(c2) : 0.f;
            float v3 = (j + 48 + slot < e) ? q2f<0>(c3) : 0.f;
            f32x2 vv0 = {v0, v0}, vv1 = {v1, v1};
            f32x2 vv2 = {v2, v2}, vv3 = {v3, v3};
            FMA16P(vv0, d0)
            FMA16P(vv1, d1)
            FMA16P(vv2, d2)
            FMA16P(vv3, d3)
        }
    }

    // epilogue-only setup: issued after the gather chain is in flight
    int dimL = dim4 * 16 + ((lane >> 2) & 1) * 8 + ((lane >> 3) & 1) * 4 +
               ((lane >> 4) & 1) * 2 + ((lane >> 5) & 1);
    float bv = bias[dimL];
    float ra = 0.f, rb = 0.f;
    if (L3) {
        ra = __builtin_nontemporal_load(xa + (size_t)row * 64 + dimL);
        rb = __builtin_nontemporal_load(xb + (size_t)row * 64 + dimL);
    }

    // re-extract scalars (constant indices -> stays in registers)
    float a[16];
#pragma unroll
    for (int k = 0; k < 16; ++k) a[k] = a2[k >> 1][k & 1];

    // recursive-halving reduce over 16 slots with dim-splitting:
    // each round keep half the dims, donate the other half to the partner.
    float r8[8];
    {
        bool h = (lane & 4) != 0;
#pragma unroll
        for (int k = 0; k < 8; ++k) {
            float keep = h ? a[8 + k] : a[k];
            float give = h ? a[k] : a[8 + k];
            r8[k] = keep + __shfl_xor(give, 4, 64);
        }
    }
    float r4[4];
    {
        bool h = (lane & 8) != 0;
#pragma unroll
        for (int k = 0; k < 4; ++k) {
            float keep = h ? r8[4 + k] : r8[k];
            float give = h ? r8[k] : r8[4 + k];
            r4[k] = keep + __shfl_xor(give, 8, 64);
        }
    }
    float r2[2];
    {
        bool h = (lane & 16) != 0;
#pragma unroll
        for (int k = 0; k < 2; ++k) {
            float keep = h ? r4[2 + k] : r4[k];
            float give = h ? r4[k] : r4[2 + k];
            r2[k] = keep + __shfl_xor(give, 16, 64);
        }
    }
    float tot;
    {
        bool h = (lane & 32) != 0;
        float keep = h ? r2[1] : r2[0];
        float give = h ? r2[0] : r2[1];
        tot = keep + __shfl_xor(give, 32, 64);
    }

    float o = fmaxf(fmaf(tot, 0.0625f, bv), 0.f);
    if (L3) o += ra + rb;
    xout[(size_t)row * 64 + dimL] = o;  // all 64 lanes store (256B/row)
}

// Pool: batch sorted -> run-length accumulate NODE_CHUNK nodes per wave, one
// atomicAdd per segment boundary per lane. h already = x1+x2+x3.
#define NODE_CHUNK 16
__global__ void pool_k(const float* __restrict__ h, const int* __restrict__ batch,
                       float* __restrict__ sums, int* __restrict__ cnts, int n) {
    int lane = threadIdx.x & 63;
    int w = (blockIdx.x * blockDim.x + threadIdx.x) >> 6;
    int node0 = w * NODE_CHUNK;
    if (node0 >= n) return;
    int cur = batch[node0];
    float acc = 0.f;
    int cnt = 0;
    int end = min(node0 + NODE_CHUNK, n);
    for (int nd = node0; nd < end; ++nd) {
        int bg = batch[nd];  // wave-uniform
        if (bg != cur) {
            atomicAdd(&sums[(size_t)cur * 64 + lane], acc);
            if (lane == 0) atomicAdd(&cnts[cur], cnt);
            acc = 0.f;
            cnt = 0;
            cur = bg;
        }
        acc += h[(size_t)nd * 64 + lane];
        cnt++;
    }
    atomicAdd(&sums[(size_t)cur * 64 + lane], acc);
    if (lane == 0) atomicAdd(&cnts[cur], cnt);
}

// Head: pooled = sums/(3*cnt); out = softmax(pooled @ Wl + bl). Wave per graph.
__global__ void final_k(const float* __restrict__ sums, const int* __restrict__ cnts,
                        const float* __restrict__ Wl, const float* __restrict__ bl,
                        float* __restrict__ out, int G) {
    int lane = threadIdx.x & 63;
    int g = (blockIdx.x * blockDim.x + threadIdx.x) >> 6;
    if (g >= G) return;
    float c = (float)max(cnts[g], 1);
    float s = sums[(size_t)g * 64 + lane] / (3.f * c);
    float y = (lane < 10) ? bl[lane] : -1e30f;
    for (int k = 0; k < 64; ++k) {
        float sk = __shfl(s, k, 64);
        if (lane < 10) y = fmaf(sk, Wl[k * 10 + lane], y);
    }
    float m = y;
#pragma unroll
    for (int off = 8; off; off >>= 1) m = fmaxf(m, __shfl_xor(m, off, 16));
    float ey = (lane < 10) ? __expf(y - m) : 0.f;
    float sm = ey;
#pragma unroll
    for (int off = 8; off; off >>= 1) sm += __shfl_xor(sm, off, 16);
    if (lane < 10) out[(size_t)g * 10 + lane] = ey / sm;
}

extern "C" void kernel_launch(void* const* d_in, const int* in_sizes, int n_in,
                              void* d_out, int out_size, void* d_ws, size_t ws_size,
                              hipStream_t stream) {
    const float* x = (const float*)d_in[0];
    const int* rows = (const int*)d_in[1];
    const int* cols = (const int*)d_in[2];
    const float* vals = (const float*)d_in[3];
    const int* batch = (const int*)d_in[4];
    const float* W1 = (const float*)d_in[5];
    const float* b1 = (const float*)d_in[6];
    const float* W2 = (const float*)d_in[7];
    const float* b2 = (const float*)d_in[8];
    const float* W3 = (const float*)d_in[9];
    const float* b3 = (const float*)d_in[10];
    const float* Wl = (const float*)d_in[11];
    const float* bl = (const float*)d_in[12];
    float* out = (float*)d_out;

    const int N = in_sizes[4];   // n_nodes (<= 131072)
    const int E = in_sizes[1];   // n_edges
    const int G = out_size / 10; // n_graphs
    const int K = (N + BROWS - 1) >> BSHIFT;
    const int C = E / K + 4096;  // fixed bucket capacity (32-sigma safe)

    char* p = (char*)d_ws;
    size_t off = 0;
    auto alloc = [&](size_t bytes) -> void* {
        off = (off + 255) & ~(size_t)255;
        void* r = (void*)(p + off);
        off += bytes;
        return r;
    };
    size_t featF = (size_t)N * 64 * 4;
    size_t pkB = (size_t)K * C * 8;
    int* bhist = (int*)alloc(MAXK * 4);
    int* bstart = (int*)alloc((MAXK + 1) * 4);
    int* bcur = (int*)alloc(MAXK * 16 * 4);
    int* rp = (int*)alloc((size_t)(N + 2) * 4);
    // pk (bucketed, pre-sort) is dead after sort_k; alias with h (written
    // only by the layer-3 spmm, far after sort_k).
    void* regP = alloc(pkB > featF ? pkB : featF);
    unsigned* epk = (unsigned*)alloc((size_t)E * 4);  // packed sorted edges
    unsigned char* ZqA = (unsigned char*)alloc((size_t)N * 64);
    unsigned char* ZqB = (unsigned char*)alloc((size_t)N * 64);
    float* x1 = (float*)alloc(featF);
    float* x2 = (float*)alloc(featF);
    float* sums = (float*)alloc((size_t)G * 64 * 4);
    int* cnts = (int*)alloc((size_t)G * 4);

    unsigned long long* pk = (unsigned long long*)regP;
    float* h = (float*)regP;

    int cb = (E + CHUNK - 1) / CHUNK;
    init_k<<<32, 256, 0, stream>>>(bhist, bcur, sums, cnts, K, C, G);
    binpass_k<<<cb, 512, 0, stream>>>(rows, cols, vals, bcur, bhist, pk, E);
    bscan_k<<<1, MAXK, 0, stream>>>(bhist, bstart, rp, K, E, N);
    sort_k<<<K, 1024, 0, stream>>>(bstart, bhist, pk, rp, epk, N, C);

    int rb = (N + 3) / 4;  // wave-per-row blocks
    dense5_k<<<rb, 256, 0, stream>>>(x, W1, ZqA, N);
    spmm16_k<0><<<rb, 256, 0, stream>>>(rp, epk, ZqA, b1, nullptr, nullptr, x1, N);
    dense64_k<<<512, 256, 0, stream>>>(x1, W2, ZqB, N);
    spmm16_k<0><<<rb, 256, 0, stream>>>(rp, epk, ZqB, b2, nullptr, nullptr, x2, N);
    dense64_k<<<512, 256, 0, stream>>>(x2, W3, ZqA, N);
    spmm16_k<1><<<rb, 256, 0, stream>>>(rp, epk, ZqA, b3, x1, x2, h, N);

    int pw = (N + NODE_CHUNK - 1) / NODE_CHUNK;
    pool_k<<<(pw + 3) / 4, 256, 0, stream>>>(h, batch, sums, cnts, N);
    final_k<<<(G + 3) / 4, 256, 0, stream>>>(sums, cnts, Wl, bl, out, G);
}

// Round 15
// 339.415 us; speedup vs baseline: 1.3307x; 1.0007x over previous
//
#include <hip/hip_runtime.h>

// GCN3: 3x (COO spmm -> Linear(64) -> ReLU), segment-mean pool, softmax head.
// relu(spmm(X)@W + b) == relu(spmm(X@W) + b): dense transform first, then
// PULL-spmm from fp8 Z (e4m3, 64B/row). Edge record 4B: (col<<14)|fp8(val*16)
// (col pre-scaled so gather byte-offset is just rec>>8).
// spmm v11: deg-ADAPTIVE single burst per row; deg<=32 -> 32-slot predicated
// burst, else 64-slot; ONE serial memory round per row (v8 invariant).
// v12 ERRATA: L2-resident Z halves cut traffic but doubled wave count at
// fixed chain latency -> slower. spmm duration = lifetime x waves, not bytes.
// CSR build v15: (a) binpass CHUNK 6144->4096: LDS 52->36KB lifts occupancy
// 3->4 blocks/CU (was 27% occ / 13% HBM / 12% VALU = latency-starved);
// (b) bscan_k dispatch ELIMINATED -- each sort_k block computes its own
// bucket prefix from bhist (parallel 256-elem LDS scan); init_k writes
// rp[N]=E. v14: bhist pass already folded into binpass via fixed-capacity
// pk buckets (C = E/K + 4096, 32-sigma safe).
// DO NOT replace build with direct global scatter (v9 ERRATA): 4B scatter
// lines fed from multiple XCDs = 16x write amplification (measured 195MB for
// 12.8MB); binpass guarantees every epk line is produced by ONE CU.
// dense64: MFMA 16x16x32 bf16, W staged in LDS per block.

#define BSHIFT 9
#define BROWS  (1 << BSHIFT)   // 512 rows per bucket
#define MAXK   256             // supports N <= 131072
#define CHUNK  4096            // edges per binpass block (32KB staging)

typedef float f32x2 __attribute__((ext_vector_type(2)));
typedef float f32x4 __attribute__((ext_vector_type(4)));
typedef unsigned u32x4 __attribute__((ext_vector_type(4)));
typedef short bf16x8 __attribute__((ext_vector_type(8)));

__device__ inline unsigned char f2q(float f) {  // fp8 e4m3 RNE (saturating)
    unsigned p = __builtin_amdgcn_cvt_pk_fp8_f32(f, f, 0u, false);
    return (unsigned char)(p & 0xffu);
}
template <int SEL>
__device__ inline float q2f(unsigned q) {  // byte-select fp8->f32 (SEL = ICE)
    return __builtin_amdgcn_cvt_f32_fp8(q, SEL);
}
template <int HI>  // 2 fp8 (bytes 2*HI, 2*HI+1) -> 2 f32, one instr
__device__ inline f32x2 q2f2(unsigned q) {
#if __has_builtin(__builtin_amdgcn_cvt_pk_f32_fp8)
    return __builtin_amdgcn_cvt_pk_f32_fp8(q, HI != 0);
#else
    f32x2 r;
    r.x = q2f<2 * HI>(q);
    r.y = q2f<2 * HI + 1>(q);
    return r;
#endif
}

// pack 8 f32 (k ascending: lo.x..lo.w, hi.x..hi.w) -> bf16x8, RNE
__device__ inline bf16x8 pack_bf8(f32x4 lo, f32x4 hi) {
    union { u32x4 u; bf16x8 h; } r;
    asm("v_cvt_pk_bf16_f32 %0, %1, %2" : "=v"(r.u.x) : "v"(lo.x), "v"(lo.y));
    asm("v_cvt_pk_bf16_f32 %0, %1, %2" : "=v"(r.u.y) : "v"(lo.z), "v"(lo.w));
    asm("v_cvt_pk_bf16_f32 %0, %1, %2" : "=v"(r.u.z) : "v"(hi.x), "v"(hi.y));
    asm("v_cvt_pk_bf16_f32 %0, %1, %2" : "=v"(r.u.w) : "v"(hi.z), "v"(hi.w));
    return r.h;
}

// Tiny init: zero bhist, set fixed-capacity bucket cursors, zero pool bufs,
// rp[N]=E. Replaces the full-E bhist pass + part of bscan.
__global__ __launch_bounds__(256) void init_k(int* __restrict__ bhist,
                                              int* __restrict__ bcur,
                                              float* __restrict__ sums,
                                              int* __restrict__ cnts,
                                              int* __restrict__ rp,
                                              int K, int C, int G,
                                              int E, int N) {
    int gid = blockIdx.x * 256 + threadIdx.x, gstep = gridDim.x * 256;
    for (int i = gid; i < MAXK; i += gstep) bhist[i] = 0;
    for (int i = gid; i < K; i += gstep) bcur[i * 16] = i * C;
    f32x4* s4 = (f32x4*)sums;
    for (int i = gid; i < G * 16; i += gstep) s4[i] = 0;
    for (int i = gid; i < G; i += gstep) cnts[i] = 0;
    if (gid == 0) rp[N] = E;
}

// Bin edges by 512-row bucket into FIXED-CAPACITY pk regions ([b*C, ...)),
// staged in LDS so global writes are single-CU bursts. Also accumulates the
// global bucket histogram. CHUNK 4096 -> 36KB LDS -> 4 blocks/CU (v15).
// Record (u64): lo32=(col<<9)|(row&511), hi32=val bits.
__global__ __launch_bounds__(512) void binpass_k(
    const int* __restrict__ rows, const int* __restrict__ cols,
    const float* __restrict__ vals, int* __restrict__ bcur,
    int* __restrict__ bhist, unsigned long long* __restrict__ pk, int E) {
    __shared__ int h[MAXK], base[MAXK], gbase[MAXK], lcnt[MAXK];
    __shared__ unsigned long long st[CHUNK];  // 32 KB
    int tx = threadIdx.x;
    if (tx < MAXK) h[tx] = 0;
    __syncthreads();
    int e0 = blockIdx.x * CHUNK, ee = min(e0 + CHUNK, E);
    for (int e = e0 + tx; e < ee; e += 512)
        atomicAdd(&h[rows[e] >> BSHIFT], 1);
    __syncthreads();
    int v = (tx < MAXK) ? h[tx] : 0;
    if (tx < MAXK) {
        lcnt[tx] = v;  // scan buffer
        if (v) atomicAdd(&bhist[tx], v);  // global bucket histogram
    }
    __syncthreads();
    for (int off = 1; off < MAXK; off <<= 1) {
        int t = (tx >= off && tx < MAXK) ? lcnt[tx - off] : 0;
        __syncthreads();
        if (tx < MAXK) lcnt[tx] += t;
        __syncthreads();
    }
    if (tx < MAXK) {
        base[tx] = lcnt[tx] - v;
        if (v) gbase[tx] = atomicAdd(&bcur[tx * 16], v);
        lcnt[tx] = 0;
    }
    __syncthreads();
    for (int e = e0 + tx; e < ee; e += 512) {
        int r = rows[e];
        int c = cols[e];
        float vv = vals[e];
        int b = r >> BSHIFT;
        int p = base[b] + atomicAdd(&lcnt[b], 1);
        unsigned lo = ((unsigned)c << BSHIFT) | (unsigned)(r & (BROWS - 1));
        st[p] = (unsigned long long)lo
              | ((unsigned long long)(unsigned)__float_as_int(vv) << 32);
    }
    __syncthreads();
    // flush contiguous per-bucket runs, wave-parallel.
    int lane = tx & 63, wid = tx >> 6;
    for (int b = wid; b < MAXK; b += 8) {
        int cnt = h[b];
        if (!cnt) continue;
        int lb = base[b], gb = gbase[b];
        for (int i = lane; i < cnt; i += 64)
            __builtin_nontemporal_store(st[lb + i], &pk[gb + i]);
    }
}

// Per-bucket counting sort: one 1024-thread block per bucket. Each block
// computes its own bucket prefix (bstart) from bhist via LDS scan (v15:
// replaces the serial bscan dispatch). Window = [b*C, b*C + bhist[b]).
// CACHED loads/stores (sub-line scatter within ONE block's window: single-CU
// line production, L2-local assembly -- v9-ERRATA-safe).
// Output record (4B): (col << 14) | fp8(val * 16).
__global__ __launch_bounds__(1024) void sort_k(
    const int* __restrict__ bhist, const unsigned long long* __restrict__ pk,
    int* __restrict__ rp, unsigned* __restrict__ epk, int n, int C) {
    __shared__ int hist[BROWS], cur[BROWS], bsc[MAXK];
    int tx = threadIdx.x;
    int b = blockIdx.x;
    int row0 = b << BSHIFT;
    // inclusive scan of bhist -> this bucket's output base eb
    if (tx < MAXK) bsc[tx] = bhist[tx];
    __syncthreads();
    for (int off = 1; off < MAXK; off <<= 1) {
        int t = (tx >= off && tx < MAXK) ? bsc[tx - off] : 0;
        __syncthreads();
        if (tx < MAXK) bsc[tx] += t;
        __syncthreads();
    }
    int s = b * C;
    int e = s + bhist[b];
    int eb = bsc[b] - bhist[b];  // exclusive prefix
    if (tx < BROWS) hist[tx] = 0;
    __syncthreads();
    for (int j = s + tx; j < e; j += 1024) {
        unsigned lo = (unsigned)pk[j];
        atomicAdd(&hist[lo & (BROWS - 1)], 1);
    }
    __syncthreads();
    int v = (tx < BROWS) ? hist[tx] : 0;
    for (int off = 1; off < BROWS; off <<= 1) {
        int t = (tx >= off && tx < BROWS) ? hist[tx - off] : 0;
        __syncthreads();
        if (tx < BROWS) hist[tx] += t;
        __syncthreads();
    }
    if (tx < BROWS) {
        int excl = hist[tx] - v;
        cur[tx] = excl;
        if (row0 + tx < n) rp[row0 + tx] = eb + excl;
    }
    __syncthreads();
    for (int j = s + tx; j < e; j += 1024) {
        unsigned long long rec = pk[j];
        unsigned lo = (unsigned)rec;
        float vv = __int_as_float((int)(unsigned)(rec >> 32));
        int r = (int)(lo & (BROWS - 1));
        int q = atomicAdd(&cur[r], 1);
        epk[eb + q] = ((lo >> BSHIFT) << 14) | (unsigned)f2q(vv * 16.f);
    }
}

// Zq = fp8(X @ W1), X:[n,5]. Wave per row, lane = out dim.
__global__ __launch_bounds__(256) void dense5_k(
    const float* __restrict__ X, const float* __restrict__ W,
    unsigned char* __restrict__ Zq, int n) {
    int lane = threadIdx.x & 63;
    int row = (blockIdx.x * blockDim.x + threadIdx.x) >> 6;
    if (row >= n) return;
    float w0 = W[lane], w1 = W[64 + lane], w2 = W[128 + lane],
          w3 = W[192 + lane], w4 = W[256 + lane];
    float xv = (lane < 5) ? X[(size_t)row * 5 + lane] : 0.f;
    float y = __shfl(xv, 0, 64) * w0;
    y = fmaf(__shfl(xv, 1, 64), w1, y);
    y = fmaf(__shfl(xv, 2, 64), w2, y);
    y = fmaf(__shfl(xv, 3, 64), w3, y);
    y = fmaf(__shfl(xv, 4, 64), w4, y);
    Zq[(size_t)row * 64 + lane] = f2q(y);
}

// dense64: Zq = fp8(X @ W) via mfma_f32_16x16x32_bf16. W staged into LDS
// coalesced once per block. LDS stride 65 -> conflict-free fragment reads.
// Wave = 16-row tile x 64 cols; frag (c,m) holds B[k=32m+8lk+i][col=16c+l15].
__global__ __launch_bounds__(256, 4) void dense64_k(
    const float* __restrict__ X, const float* __restrict__ W,
    unsigned char* __restrict__ Zq, int n) {
    __shared__ float wlds[64 * 65];
    int tx = threadIdx.x;
    int lane = tx & 63, wid = tx >> 6;
    int l15 = lane & 15, lk = lane >> 4;
#pragma unroll
    for (int i = 0; i < 16; ++i) {
        int idx = i * 256 + tx;              // coalesced: 1KB per instr
        wlds[(idx >> 6) * 65 + (idx & 63)] = W[idx];
    }
    __syncthreads();
    bf16x8 bw[4][2];
#pragma unroll
    for (int c = 0; c < 4; ++c) {
#pragma unroll
        for (int m = 0; m < 2; ++m) {
            const float* wp = wlds + (32 * m + 8 * lk) * 65 + 16 * c + l15;
            f32x4 lo, hi;
            lo.x = wp[0];       lo.y = wp[65];      lo.z = wp[130];  lo.w = wp[195];
            hi.x = wp[260];     hi.y = wp[325];     hi.z = wp[390];  hi.w = wp[455];
            bw[c][m] = pack_bf8(lo, hi);
        }
    }
    int nt = (n + 15) >> 4;
    int nwv = (int)(gridDim.x * 4);
    for (int t = blockIdx.x * 4 + wid; t < nt; t += nwv) {
        int rowb = t << 4;
        int ar = min(rowb + l15, n - 1);  // clamped A row (stores guarded)
        const float* xr = X + (size_t)ar * 64 + 8 * lk;
        f32x4 a0 = *(const f32x4*)(xr);
        f32x4 a1 = *(const f32x4*)(xr + 4);
        f32x4 a2 = *(const f32x4*)(xr + 32);
        f32x4 a3 = *(const f32x4*)(xr + 36);
        bf16x8 A0 = pack_bf8(a0, a1);
        bf16x8 A1 = pack_bf8(a2, a3);
        f32x4 acc0 = 0, acc1 = 0, acc2 = 0, acc3 = 0;
        acc0 = __builtin_amdgcn_mfma_f32_16x16x32_bf16(A0, bw[0][0], acc0, 0, 0, 0);
        acc1 = __builtin_amdgcn_mfma_f32_16x16x32_bf16(A0, bw[1][0], acc1, 0, 0, 0);
        acc2 = __builtin_amdgcn_mfma_f32_16x16x32_bf16(A0, bw[2][0], acc2, 0, 0, 0);
        acc3 = __builtin_amdgcn_mfma_f32_16x16x32_bf16(A0, bw[3][0], acc3, 0, 0, 0);
        acc0 = __builtin_amdgcn_mfma_f32_16x16x32_bf16(A1, bw[0][1], acc0, 0, 0, 0);
        acc1 = __builtin_amdgcn_mfma_f32_16x16x32_bf16(A1, bw[1][1], acc1, 0, 0, 0);
        acc2 = __builtin_amdgcn_mfma_f32_16x16x32_bf16(A1, bw[2][1], acc2, 0, 0, 0);
        acc3 = __builtin_amdgcn_mfma_f32_16x16x32_bf16(A1, bw[3][1], acc3, 0, 0, 0);
#pragma unroll
        for (int j = 0; j < 4; ++j) {
            int r = rowb + 4 * lk + j;
            if (r < n) {
                unsigned char* zp = Zq + (size_t)r * 64 + l15;
                zp[0]  = f2q(acc0[j]);
                zp[16] = f2q(acc1[j]);
                zp[32] = f2q(acc2[j]);
                zp[48] = f2q(acc3[j]);
            }
        }
    }
}

// Packed core: one edge's 16B Zq chunk into a2[0..7] (f32x2 = 2 dims each).
// 8 cvt_pk + 8 pk_fma per edge.
#define FMA16P(vv2, d)                                                         \
    a2[0] += (vv2) * q2f2<0>((d).x);                                           \
    a2[1] += (vv2) * q2f2<1>((d).x);                                           \
    a2[2] += (vv2) * q2f2<0>((d).y);                                           \
    a2[3] += (vv2) * q2f2<1>((d).y);                                           \
    a2[4] += (vv2) * q2f2<0>((d).z);                                           \
    a2[5] += (vv2) * q2f2<1>((d).z);                                           \
    a2[6] += (vv2) * q2f2<0>((d).w);                                           \
    a2[7] += (vv2) * q2f2<1>((d).w);

// spmm v11: wave per row; 16 edge-slots (lane>>2) x 4 dim-lanes (lane&3).
// Deg-adaptive single predicated burst (32 or 64 slots, wave-uniform
// branch); idx clamped to e-1, v masked 0. Zq NaN-free (cvt saturates).
template <int L3>
__global__ __launch_bounds__(256, 8) void spmm16_k(
    const int* __restrict__ rp, const unsigned* __restrict__ epk,
    const unsigned char* __restrict__ Zq, const float* __restrict__ bias,
    const float* __restrict__ xa, const float* __restrict__ xb,
    float* __restrict__ xout, int n) {
    int lane = threadIdx.x & 63;
    int dim4 = lane & 3, slot = lane >> 2;
    int row = __builtin_amdgcn_readfirstlane(
        (int)((blockIdx.x * blockDim.x + threadIdx.x) >> 6));
    if (row >= n) return;
    int s = rp[row], e = rp[row + 1];    // scalar loads (wave-uniform row)
    const unsigned char* zb = Zq + (dim4 << 4);

    f32x2 a2[8];
#pragma unroll
    for (int k = 0; k < 8; ++k) a2[k] = 0;

    if (e - s <= 32) {  // ~55% of rows (Poisson(32)): 32-slot burst
        int i0 = min(s + slot, e - 1);
        int i1 = min(s + 16 + slot, e - 1);
        unsigned c0 = __builtin_nontemporal_load(epk + i0);
        unsigned c1 = __builtin_nontemporal_load(epk + i1);
        u32x4 d0 = *(const u32x4*)(zb + (c0 >> 8));  // c>>8 = col*64
        u32x4 d1 = *(const u32x4*)(zb + (c1 >> 8));
        float v0 = (s + slot < e) ? q2f<0>(c0) : 0.f;
        float v1 = (s + 16 + slot < e) ? q2f<0>(c1) : 0.f;
        f32x2 vv0 = {v0, v0}, vv1 = {v1, v1};
        FMA16P(vv0, d0)
        FMA16P(vv1, d1)
    } else {
        int j = s;
        for (; j + 64 <= e; j += 64) {  // rare (P ~ 6e-7): full 64-bursts
            unsigned c0 = __builtin_nontemporal_load(epk + j + slot);
            unsigned c1 = __builtin_nontemporal_load(epk + j + 16 + slot);
            unsigned c2 = __builtin_nontemporal_load(epk + j + 32 + slot);
            unsigned c3 = __builtin_nontemporal_load(epk + j + 48 + slot);
            u32x4 d0 = *(const u32x4*)(zb + (c0 >> 8));
            u32x4 d1 = *(const u32x4*)(zb + (c1 >> 8));
            u32x4 d2 = *(const u32x4*)(zb + (c2 >> 8));
            u32x4 d3 = *(const u32x4*)(zb + (c3 >> 8));
            float v0 = q2f<0>(c0), v1 = q2f<0>(c1);
            float v2 = q2f<0>(c2), v3 = q2f<0>(c3);
            f32x2 vv0 = {v0, v0}, vv1 = {v1, v1};
            f32x2 vv2 = {v2, v2}, vv3 = {v3, v3};
            FMA16P(vv0, d0)
            FMA16P(vv1, d1)
            FMA16P(vv2, d2)
            FMA16P(vv3, d3)
        }
        if (j < e) {  // 33..64 edges left: one 64-slot predicated burst
            int i0 = min(j + slot, e - 1);
            int i1 = min(j + 16 + slot, e - 1);
            int i2 = min(j + 32 + slot, e - 1);
            int i3 = min(j + 48 + slot, e - 1);
            unsigned c0 = __builtin_nontemporal_load(epk + i0);
            unsigned c1 = __builtin_nontemporal_load(epk + i1);
            unsigned c2 = __builtin_nontemporal_load(epk + i2);
            unsigned c3 = __builtin_nontemporal_load(epk + i3);
            u32x4 d0 = *(const u32x4*)(zb + (c0 >> 8));
            u32x4 d1 = *(const u32x4*)(zb + (c1 >> 8));
            u32x4 d2 = *(const u32x4*)(zb + (c2 >> 8));
            u32x4 d3 = *(const u32x4*)(zb + (c3 >> 8));
            float v0 = (j + slot < e) ? q2f<0>(c0) : 0.f;
            float v1 = (j + 16 + slot < e) ? q2f<0>(c1) : 0.f;
            float v2 = (j + 32 + slot < e) ? q2f<0>(c2) : 0.f;
            float v3 = (j + 48 + slot < e) ? q2f<0>(c3) : 0.f;
            f32x2 vv0 = {v0, v0}, vv1 = {v1, v1};
            f32x2 vv2 = {v2, v2}, vv3 = {v3, v3};
            FMA16P(vv0, d0)
            FMA16P(vv1, d1)
            FMA16P(vv2, d2)
            FMA16P(vv3, d3)
        }
    }

    // epilogue-only setup: issued after the gather chain is in flight
    int dimL = dim4 * 16 + ((lane >> 2) & 1) * 8 + ((lane >> 3) & 1) * 4 +
               ((lane >> 4) & 1) * 2 + ((lane >> 5) & 1);
    float bv = bias[dimL];
    float ra = 0.f, rb = 0.f;
    if (L3) {
        ra = __builtin_nontemporal_load(xa + (size_t)row * 64 + dimL);
        rb = __builtin_nontemporal_load(xb + (size_t)row * 64 + dimL);
    }

    // re-extract scalars (constant indices -> stays in registers)
    float a[16];
#pragma unroll
    for (int k = 0; k < 16; ++k) a[k] = a2[k >> 1][k & 1];

    // recursive-halving reduce over 16 slots with dim-splitting:
    // each round keep half the dims, donate the other half to the partner.
    float r8[8];
    {
        bool h = (lane & 4) != 0;
#pragma unroll
        for (int k = 0; k < 8; ++k) {
            float keep = h ? a[8 + k] : a[k];
            float give = h ? a[k] : a[8 + k];
            r8[k] = keep + __shfl_xor(give, 4, 64);
        }
    }
    float r4[4];
    {
        bool h = (lane & 8) != 0;
#pragma unroll
        for (int k = 0; k < 4; ++k) {
            float keep = h ? r8[4 + k] : r8[k];
            float give = h ? r8[k] : r8[4 + k];
            r4[k] = keep + __shfl_xor(give, 8, 64);
        }
    }
    float r2[2];
    {
        bool h = (lane & 16) != 0;
#pragma unroll
        for (int k = 0; k < 2; ++k) {
            float keep = h ? r4[2 + k] : r4[k];
            float give = h ? r4[k] : r4[2 + k];
            r2[k] = keep + __shfl_xor(give, 16, 64);
        }
    }
    float tot;
    {
        bool h = (lane & 32) != 0;
        float keep = h ? r2[1] : r2[0];
        float give = h ? r2[0] : r2[1];
        tot = keep + __shfl_xor(give, 32, 64);
    }

    float o = fmaxf(fmaf(tot, 0.0625f, bv), 0.f);
    if (L3) o += ra + rb;
    xout[(size_t)row * 64 + dimL] = o;  // all 64 lanes store (256B/row)
}

// Pool: batch sorted -> run-length accumulate NODE_CHUNK nodes per wave, one
// atomicAdd per segment boundary per lane. h already = x1+x2+x3.
#define NODE_CHUNK 16
__global__ void pool_k(const float* __restrict__ h, const int* __restrict__ batch,
                       float* __restrict__ sums, int* __restrict__ cnts, int n) {
    int lane = threadIdx.x & 63;
    int w = (blockIdx.x * blockDim.x + threadIdx.x) >> 6;
    int node0 = w * NODE_CHUNK;
    if (node0 >= n) return;
    int cur = batch[node0];
    float acc = 0.f;
    int cnt = 0;
    int end = min(node0 + NODE_CHUNK, n);
    for (int nd = node0; nd < end; ++nd) {
        int bg = batch[nd];  // wave-uniform
        if (bg != cur) {
            atomicAdd(&sums[(size_t)cur * 64 + lane], acc);
            if (lane == 0) atomicAdd(&cnts[cur], cnt);
            acc = 0.f;
            cnt = 0;
            cur = bg;
        }
        acc += h[(size_t)nd * 64 + lane];
        cnt++;
    }
    atomicAdd(&sums[(size_t)cur * 64 + lane], acc);
    if (lane == 0) atomicAdd(&cnts[cur], cnt);
}

// Head: pooled = sums/(3*cnt); out = softmax(pooled @ Wl + bl). Wave per graph.
__global__ void final_k(const float* __restrict__ sums, const int* __restrict__ cnts,
                        const float* __restrict__ Wl, const float* __restrict__ bl,
                        float* __restrict__ out, int G) {
    int lane = threadIdx.x & 63;
    int g = (blockIdx.x * blockDim.x + threadIdx.x) >> 6;
    if (g >= G) return;
    float c = (float)max(cnts[g], 1);
    float s = sums[(size_t)g * 64 + lane] / (3.f * c);
    float y = (lane < 10) ? bl[lane] : -1e30f;
    for (int k = 0; k < 64; ++k) {
        float sk = __shfl(s, k, 64);
        if (lane < 10) y = fmaf(sk, Wl[k * 10 + lane], y);
    }
    float m = y;
#pragma unroll
    for (int off = 8; off; off >>= 1) m = fmaxf(m, __shfl_xor(m, off, 16));
    float ey = (lane < 10) ? __expf(y - m) : 0.f;
    float sm = ey;
#pragma unroll
    for (int off = 8; off; off >>= 1) sm += __shfl_xor(sm, off, 16);
    if (lane < 10) out[(size_t)g * 10 + lane] = ey / sm;
}

extern "C" void kernel_launch(void* const* d_in, const int* in_sizes, int n_in,
                              void* d_out, int out_size, void* d_ws, size_t ws_size,
                              hipStream_t stream) {
    const float* x = (const float*)d_in[0];
    const int* rows = (const int*)d_in[1];
    const int* cols = (const int*)d_in[2];
    const float* vals = (const float*)d_in[3];
    const int* batch = (const int*)d_in[4];
    const float* W1 = (const float*)d_in[5];
    const float* b1 = (const float*)d_in[6];
    const float* W2 = (const float*)d_in[7];
    const float* b2 = (const float*)d_in[8];
    const float* W3 = (const float*)d_in[9];
    const float* b3 = (const float*)d_in[10];
    const float* Wl = (const float*)d_in[11];
    const float* bl = (const float*)d_in[12];
    float* out = (float*)d_out;

    const int N = in_sizes[4];   // n_nodes (<= 131072)
    const int E = in_sizes[1];   // n_edges
    const int G = out_size / 10; // n_graphs
    const int K = (N + BROWS - 1) >> BSHIFT;
    const int C = E / K + 4096;  // fixed bucket capacity (32-sigma safe)

    char* p = (char*)d_ws;
    size_t off = 0;
    auto alloc = [&](size_t bytes) -> void* {
        off = (off + 255) & ~(size_t)255;
        void* r = (void*)(p + off);
        off += bytes;
        return r;
    };
    size_t featF = (size_t)N * 64 * 4;
    size_t pkB = (size_t)K * C * 8;
    int* bhist = (int*)alloc(MAXK * 4);
    int* bcur = (int*)alloc(MAXK * 16 * 4);
    int* rp = (int*)alloc((size_t)(N + 2) * 4);
    // pk (bucketed, pre-sort) is dead after sort_k; alias with h (written
    // only by the layer-3 spmm, far after sort_k).
    void* regP = alloc(pkB > featF ? pkB : featF);
    unsigned* epk = (unsigned*)alloc((size_t)E * 4);  // packed sorted edges
    unsigned char* ZqA = (unsigned char*)alloc((size_t)N * 64);
    unsigned char* ZqB = (unsigned char*)alloc((size_t)N * 64);
    float* x1 = (float*)alloc(featF);
    float* x2 = (float*)alloc(featF);
    float* sums = (float*)alloc((size_t)G * 64 * 4);
    int* cnts = (int*)alloc((size_t)G * 4);

    unsigned long long* pk = (unsigned long long*)regP;
    float* h = (float*)regP;

    int cb = (E + CHUNK - 1) / CHUNK;
    init_k<<<32, 256, 0, stream>>>(bhist, bcur, sums, cnts, rp, K, C, G, E, N);
    binpass_k<<<cb, 512, 0, stream>>>(rows, cols, vals, bcur, bhist, pk, E);
    sort_k<<<K, 1024, 0, stream>>>(bhist, pk, rp, epk, N, C);

    int rb = (N + 3) / 4;  // wave-per-row blocks
    dense5_k<<<rb, 256, 0, stream>>>(x, W1, ZqA, N);
    spmm16_k<0><<<rb, 256, 0, stream>>>(rp, epk, ZqA, b1, nullptr, nullptr, x1, N);
    dense64_k<<<512, 256, 0, stream>>>(x1, W2, ZqB, N);
    spmm16_k<0><<<rb, 256, 0, stream>>>(rp, epk, ZqB, b2, nullptr, nullptr, x2, N);
    dense64_k<<<512, 256, 0, stream>>>(x2, W3, ZqA, N);
    spmm16_k<1><<<rb, 256, 0, stream>>>(rp, epk, ZqA, b3, x1, x2, h, N);

    int pw = (N + NODE_CHUNK - 1) / NODE_CHUNK;
    pool_k<<<(pw + 3) / 4, 256, 0, stream>>>(h, batch, sums, cnts, N);
    final_k<<<(G + 3) / 4, 256, 0, stream>>>(sums, cnts, Wl, bl, out, G);
}